// Round 3
// baseline (1336.337 us; speedup 1.0000x reference)
//
#include <hip/hip_runtime.h>
#include <hip/hip_bf16.h>

#define NN 100000
#define EE 1600000
#define DD 128
#define SCAN_N (2 * NN)            // concatenated degree array: [dst-counts | src-counts]
#define SCAN_BLOCKS ((SCAN_N + 1023) / 1024)   // 196

// ---------------------------------------------------------------- transpose
// All four weight matrices in one launch. out[c*R + r] = in[r*C + c].
__global__ __launch_bounds__(256) void k_transpose_all(const float* __restrict__ W1,
                                                       const float* __restrict__ W2,
                                                       const float* __restrict__ Wl1,
                                                       const float* __restrict__ Wl2,
                                                       float* __restrict__ Wt1,
                                                       float* __restrict__ Wt2,
                                                       float* __restrict__ Wtl1,
                                                       float* __restrict__ Wtl2) {
    int tid = blockIdx.x * 256 + threadIdx.x;   // 131072 threads total
    const float* in;
    float* out;
    int C, R, off;
    if (tid < 16384)      { in = W1;  out = Wt1;  R = 128; C = 128; off = 0; }
    else if (tid < 32768) { in = W2;  out = Wt2;  R = 128; C = 128; off = 16384; }
    else if (tid < 98304) { in = Wl1; out = Wtl1; R = 256; C = 256; off = 32768; }
    else                  { in = Wl2; out = Wtl2; R = 128; C = 256; off = 98304; }
    int i = tid - off;
    int r = i / C, c = i - r * C;
    out[c * R + r] = in[i];
}

// ---------------------------------------------------------------- CSR build
// off[] initially holds counts: off[d] = in-degree(d) (CSR1, edges grouped by
// dst holding src), off[NN+s] = out-degree(s) (CSR2, grouped by src holding
// dst). After scan, off[g] is the bucket start in the shared idx[2E] array.
__global__ __launch_bounds__(256) void k_count(const int* __restrict__ ei,
                                               int* __restrict__ off) {
    int e = blockIdx.x * 256 + threadIdx.x;     // EE threads exactly
    int s = ei[e];
    int d = ei[EE + e];
    atomicAdd(&off[d], 1);
    atomicAdd(&off[NN + s], 1);
}

// scan pass 1: per-block (1024 items = 256 thr x 4) exclusive scan in place,
// block totals to bsum[].
__global__ __launch_bounds__(256) void k_scan1(int* __restrict__ off,
                                               int* __restrict__ bsum) {
    __shared__ int s[256];
    int t = threadIdx.x;
    int base = blockIdx.x * 1024 + t * 4;
    int v[4];
    #pragma unroll
    for (int i = 0; i < 4; ++i) {
        int g = base + i;
        v[i] = (g < SCAN_N) ? off[g] : 0;
    }
    int local = v[0] + v[1] + v[2] + v[3];
    s[t] = local;
    __syncthreads();
    #pragma unroll
    for (int o = 1; o < 256; o <<= 1) {
        int add = (t >= o) ? s[t - o] : 0;
        __syncthreads();
        s[t] += add;
        __syncthreads();
    }
    int run = s[t] - local;                     // exclusive prefix of this thread
    #pragma unroll
    for (int i = 0; i < 4; ++i) {
        int g = base + i;
        if (g < SCAN_N) off[g] = run;
        run += v[i];
    }
    if (t == 0) bsum[blockIdx.x] = s[255];
}

// scan pass 2: exclusive scan of the 196 block totals (single block).
__global__ __launch_bounds__(256) void k_scan2(int* __restrict__ bsum) {
    __shared__ int s[256];
    int t = threadIdx.x;
    int local = (t < SCAN_BLOCKS) ? bsum[t] : 0;
    s[t] = local;
    __syncthreads();
    #pragma unroll
    for (int o = 1; o < 256; o <<= 1) {
        int add = (t >= o) ? s[t - o] : 0;
        __syncthreads();
        s[t] += add;
        __syncthreads();
    }
    if (t < SCAN_BLOCKS) bsum[t] = s[t] - local;
}

// scan pass 3: add block bases; mirror into cur[] (fill cursors); set sentinel.
__global__ __launch_bounds__(256) void k_scan3(int* __restrict__ off,
                                               const int* __restrict__ bsum,
                                               int* __restrict__ cur) {
    int t = threadIdx.x;
    int base = blockIdx.x * 1024 + t * 4;
    int add = bsum[blockIdx.x];
    #pragma unroll
    for (int i = 0; i < 4; ++i) {
        int g = base + i;
        if (g < SCAN_N) {
            int v = off[g] + add;
            off[g] = v;
            cur[g] = v;
        }
    }
    if (blockIdx.x == 0 && t == 0) off[SCAN_N] = 2 * EE;   // sentinel
}

// fill: bucket(dst) <- src (CSR1 region [0,E)), bucket(NN+src) <- dst (CSR2
// region [E,2E)) -- regions fall out of the concatenated scan automatically.
__global__ __launch_bounds__(256) void k_fill(const int* __restrict__ ei,
                                              int* __restrict__ cur,
                                              int* __restrict__ idx) {
    int e = blockIdx.x * 256 + threadIdx.x;     // EE threads exactly
    int s = ei[e];
    int d = ei[EE + e];
    int p1 = atomicAdd(&cur[d], 1);
    idx[p1] = s;
    int p2 = atomicAdd(&cur[NN + s], 1);
    idx[p2] = d;
}

// ---------------------------------------------------------------- gather
// One 32-lane group per (node, branch): lane c owns float4 column c.
// h = x[n] + sum_{nbr in bucket} x[nbr]  (no float atomics anywhere).
// g < NN -> h1 (GIN branch 1, neighbors = srcs grouped by dst);
// g >= NN -> h2 (branch 2, neighbors = dsts grouped by src).
__global__ __launch_bounds__(256) void k_gather(const float4* __restrict__ x4,
                                                const int* __restrict__ off,
                                                const int* __restrict__ idx,
                                                float4* __restrict__ h1,
                                                float4* __restrict__ h2) {
    int t = threadIdx.x;
    int g = blockIdx.x * 8 + (t >> 5);          // 2N = 200000 = 25000 blocks * 8
    int c = t & 31;
    int n = (g < NN) ? g : g - NN;
    int o0 = off[g], o1 = off[g + 1];
    float4 acc = x4[n * 32 + c];                // + x (GIN eps=0 self term)
    for (int j = o0; j < o1; ++j) {
        int nbr = idx[j];                       // same addr across lanes: broadcast
        float4 v = x4[nbr * 32 + c];
        acc.x += v.x; acc.y += v.y; acc.z += v.z; acc.w += v.w;
    }
    float4* hout = (g < NN) ? h1 : h2;
    hout[n * 32 + c] = acc;
}

// ---------------------------------------------------------------- branch
// blockIdx.y selects branch. Per block: 128 nodes. h staged in LDS (stride
// 134). GEMM t = h @ W^T (Wt staged [k][n] stride 132, 4-way b-read = 1.58x).
// Epilogue: +bias, LayerNorm (shfl over 16 lanes), ReLU, residual h+y ->
// cat columns [colOff, colOff+128).
__global__ __launch_bounds__(256) void k_branch(const float* __restrict__ h1,
                                                const float* __restrict__ h2,
                                                const float* __restrict__ Wt1,
                                                const float* __restrict__ Wt2,
                                                const float* __restrict__ bias1,
                                                const float* __restrict__ bias2,
                                                const float* __restrict__ gam1,
                                                const float* __restrict__ gam2,
                                                const float* __restrict__ beta1,
                                                const float* __restrict__ beta2,
                                                float* __restrict__ cat) {
    const int br = blockIdx.y;
    const float* h    = br ? h2    : h1;
    const float* Wt   = br ? Wt2   : Wt1;
    const float* bias = br ? bias2 : bias1;
    const float* gam  = br ? gam2  : gam1;
    const float* beta = br ? beta2 : beta1;
    const int colOff  = br ? 128 : 0;

    __shared__ float hs[128 * 134];
    __shared__ float wst[128 * 132];
    int t = threadIdx.x;
    int m0 = blockIdx.x * 128;

    #pragma unroll
    for (int it = 0; it < 16; ++it) {           // stage h: 128 rows x 32 float4
        int f = it * 256 + t;
        int m = f >> 5, k4 = f & 31;
        int node = m0 + m;
        float4 h4 = make_float4(0.f, 0.f, 0.f, 0.f);
        if (node < NN) h4 = ((const float4*)h)[node * 32 + k4];
        int base = m * 134 + k4 * 4;
        *(float2*)&hs[base]     = make_float2(h4.x, h4.y);
        *(float2*)&hs[base + 2] = make_float2(h4.z, h4.w);
    }
    #pragma unroll
    for (int it = 0; it < 16; ++it) {           // stage Wt -> [k][n] stride 132
        int f = it * 256 + t;
        int k = f >> 5, n4 = f & 31;
        *(float4*)&wst[k * 132 + n4 * 4] = ((const float4*)Wt)[k * 32 + n4];
    }
    __syncthreads();

    int my = t >> 4, tx = t & 15;
    int n0 = tx * 8;
    float acc[8][8];
    #pragma unroll
    for (int i = 0; i < 8; ++i)
        #pragma unroll
        for (int j = 0; j < 8; ++j) acc[i][j] = 0.f;

    int abase = (my * 8) * 134;
    #pragma unroll 4
    for (int k = 0; k < 128; ++k) {
        float a[8];
        #pragma unroll
        for (int i = 0; i < 8; ++i) a[i] = hs[abase + i * 134 + k];
        float4 b0 = *(const float4*)&wst[k * 132 + n0];
        float4 b1 = *(const float4*)&wst[k * 132 + n0 + 4];
        float bb[8] = {b0.x, b0.y, b0.z, b0.w, b1.x, b1.y, b1.z, b1.w};
        #pragma unroll
        for (int i = 0; i < 8; ++i)
            #pragma unroll
            for (int j = 0; j < 8; ++j) acc[i][j] += a[i] * bb[j];
    }

    float breg[8], greg[8], btreg[8];
    #pragma unroll
    for (int j = 0; j < 8; ++j) {
        breg[j]  = bias[n0 + j];
        greg[j]  = gam[n0 + j];
        btreg[j] = beta[n0 + j];
    }
    #pragma unroll
    for (int i = 0; i < 8; ++i) {
        float s = 0.f, q = 0.f;
        #pragma unroll
        for (int j = 0; j < 8; ++j) {
            float v = acc[i][j] + breg[j];
            acc[i][j] = v;
            s += v;
            q += v * v;
        }
        #pragma unroll
        for (int o = 1; o < 16; o <<= 1) {
            s += __shfl_xor(s, o);
            q += __shfl_xor(q, o);
        }
        float mu  = s * (1.f / 128.f);
        float var = q * (1.f / 128.f) - mu * mu;
        float rs  = rsqrtf(var + 1e-5f);
        int m = my * 8 + i, node = m0 + m;
        if (node < NN) {
            float o[8];
            #pragma unroll
            for (int j = 0; j < 8; ++j) {
                float y = (acc[i][j] - mu) * rs * greg[j] + btreg[j];
                y = fmaxf(y, 0.f);
                o[j] = hs[m * 134 + n0 + j] + y;   // residual: ret = h + relu(LN)
            }
            float4* cp = (float4*)&cat[node * 256 + colOff + n0];
            cp[0] = make_float4(o[0], o[1], o[2], o[3]);
            cp[1] = make_float4(o[4], o[5], o[6], o[7]);
        }
    }
}

// ---------------------------------------------------------------- mlp1
// mid = relu(cat @ Wl1^T + bl1). 64 nodes x 256 outs, K=256 in quarters.
__global__ __launch_bounds__(256) void k_mlp1(const float* __restrict__ cat,
                                              const float* __restrict__ Wt,
                                              const float* __restrict__ bias,
                                              float* __restrict__ mid) {
    __shared__ float hs[64 * 258];
    __shared__ float wst[64 * 260];
    int t = threadIdx.x;
    int m0 = blockIdx.x * 64;

    #pragma unroll
    for (int it = 0; it < 16; ++it) {           // 64 rows x 64 float4
        int f = it * 256 + t;
        int m = f >> 6, k4 = f & 63;
        int node = m0 + m;
        float4 v = make_float4(0.f, 0.f, 0.f, 0.f);
        if (node < NN) v = ((const float4*)cat)[node * 64 + k4];
        int base = m * 258 + k4 * 4;
        *(float2*)&hs[base]     = make_float2(v.x, v.y);
        *(float2*)&hs[base + 2] = make_float2(v.z, v.w);
    }

    int my = t >> 5, tx = t & 31;
    int n0 = tx * 8;
    float acc[8][8];
    #pragma unroll
    for (int i = 0; i < 8; ++i)
        #pragma unroll
        for (int j = 0; j < 8; ++j) acc[i][j] = 0.f;

    for (int kq = 0; kq < 4; ++kq) {
        __syncthreads();
        #pragma unroll
        for (int it = 0; it < 16; ++it) {       // 64 k-rows x 64 float4
            int f = it * 256 + t;
            int kl = f >> 6, n4 = f & 63;
            *(float4*)&wst[kl * 260 + n4 * 4] =
                ((const float4*)Wt)[(kq * 64 + kl) * 64 + n4];
        }
        __syncthreads();
        int abase = (my * 8) * 258 + kq * 64;
        #pragma unroll 4
        for (int kl = 0; kl < 64; ++kl) {
            float a[8];
            #pragma unroll
            for (int i = 0; i < 8; ++i) a[i] = hs[abase + i * 258 + kl];
            float4 b0 = *(const float4*)&wst[kl * 260 + n0];
            float4 b1 = *(const float4*)&wst[kl * 260 + n0 + 4];
            float bb[8] = {b0.x, b0.y, b0.z, b0.w, b1.x, b1.y, b1.z, b1.w};
            #pragma unroll
            for (int i = 0; i < 8; ++i)
                #pragma unroll
                for (int j = 0; j < 8; ++j) acc[i][j] += a[i] * bb[j];
        }
    }

    float breg[8];
    #pragma unroll
    for (int j = 0; j < 8; ++j) breg[j] = bias[n0 + j];
    #pragma unroll
    for (int i = 0; i < 8; ++i) {
        int node = m0 + my * 8 + i;
        if (node < NN) {
            float o[8];
            #pragma unroll
            for (int j = 0; j < 8; ++j) o[j] = fmaxf(acc[i][j] + breg[j], 0.f);
            float4* mp = (float4*)&mid[node * 256 + n0];
            mp[0] = make_float4(o[0], o[1], o[2], o[3]);
            mp[1] = make_float4(o[4], o[5], o[6], o[7]);
        }
    }
}

// ---------------------------------------------------------------- mlp2
// out = relu(mid @ Wl2^T + bl2). 128 nodes x 128 outs, K=256 in halves.
__global__ __launch_bounds__(256) void k_mlp2(const float* __restrict__ mid,
                                              const float* __restrict__ Wt,
                                              const float* __restrict__ bias,
                                              float* __restrict__ out) {
    __shared__ float hs[128 * 130];
    __shared__ float wst[128 * 132];
    int t = threadIdx.x;
    int m0 = blockIdx.x * 128;
    int my = t >> 4, tx = t & 15;
    int n0 = tx * 8;
    float acc[8][8];
    #pragma unroll
    for (int i = 0; i < 8; ++i)
        #pragma unroll
        for (int j = 0; j < 8; ++j) acc[i][j] = 0.f;

    for (int kh = 0; kh < 2; ++kh) {
        __syncthreads();
        #pragma unroll
        for (int it = 0; it < 16; ++it) {       // 128 rows x 32 float4 (k-half)
            int f = it * 256 + t;
            int m = f >> 5, k4 = f & 31;
            int node = m0 + m;
            float4 v = make_float4(0.f, 0.f, 0.f, 0.f);
            if (node < NN) v = ((const float4*)mid)[node * 64 + kh * 32 + k4];
            int base = m * 130 + k4 * 4;
            *(float2*)&hs[base]     = make_float2(v.x, v.y);
            *(float2*)&hs[base + 2] = make_float2(v.z, v.w);
        }
        #pragma unroll
        for (int it = 0; it < 16; ++it) {       // 128 k-rows x 32 float4
            int f = it * 256 + t;
            int kl = f >> 5, n4 = f & 31;
            *(float4*)&wst[kl * 132 + n4 * 4] =
                ((const float4*)Wt)[(kh * 128 + kl) * 32 + n4];
        }
        __syncthreads();
        int abase = (my * 8) * 130;
        #pragma unroll 4
        for (int kl = 0; kl < 128; ++kl) {
            float a[8];
            #pragma unroll
            for (int i = 0; i < 8; ++i) a[i] = hs[abase + i * 130 + kl];
            float4 b0 = *(const float4*)&wst[kl * 132 + n0];
            float4 b1 = *(const float4*)&wst[kl * 132 + n0 + 4];
            float bb[8] = {b0.x, b0.y, b0.z, b0.w, b1.x, b1.y, b1.z, b1.w};
            #pragma unroll
            for (int i = 0; i < 8; ++i)
                #pragma unroll
                for (int j = 0; j < 8; ++j) acc[i][j] += a[i] * bb[j];
        }
    }

    float breg[8];
    #pragma unroll
    for (int j = 0; j < 8; ++j) breg[j] = bias[n0 + j];
    #pragma unroll
    for (int i = 0; i < 8; ++i) {
        int node = m0 + my * 8 + i;
        if (node < NN) {
            float o[8];
            #pragma unroll
            for (int j = 0; j < 8; ++j) o[j] = fmaxf(acc[i][j] + breg[j], 0.f);
            float4* op = (float4*)&out[node * 128 + n0];
            op[0] = make_float4(o[0], o[1], o[2], o[3]);
            op[1] = make_float4(o[4], o[5], o[6], o[7]);
        }
    }
}

// ---------------------------------------------------------------- launch
extern "C" void kernel_launch(void* const* d_in, const int* in_sizes, int n_in,
                              void* d_out, int out_size, void* d_ws, size_t ws_size,
                              hipStream_t stream) {
    const float* x   = (const float*)d_in[0];
    const int*   ei  = (const int*)d_in[1];
    const float* W1  = (const float*)d_in[2];
    const float* b1  = (const float*)d_in[3];
    const float* g1  = (const float*)d_in[4];
    const float* bt1 = (const float*)d_in[5];
    const float* W2  = (const float*)d_in[6];
    const float* b2  = (const float*)d_in[7];
    const float* g2  = (const float*)d_in[8];
    const float* bt2 = (const float*)d_in[9];
    const float* Wl1 = (const float*)d_in[10];
    const float* bl1 = (const float*)d_in[11];
    const float* Wl2 = (const float*)d_in[12];
    const float* bl2 = (const float*)d_in[13];
    float* out = (float*)d_out;

    // workspace layout:
    //   floats: h1[N*128] h2[N*128]  (later reused as mid[N*256])
    //           cat[N*256]
    //           Wt1[16384] Wt2[16384] Wtl1[65536] Wtl2[32768]
    //   ints:   off[2N+1] cur[2N] idx[2E] bsum[256]
    // total ~= 205MB + 0.5MB + 14.5MB
    float* ws   = (float*)d_ws;
    float* h1   = ws;
    float* h2   = ws + (size_t)NN * DD;
    float* mid  = ws;                           // reuse h region after branches
    float* cat  = ws + (size_t)2 * NN * DD;
    float* Wt1  = ws + (size_t)4 * NN * DD;
    float* Wt2  = Wt1 + 128 * 128;
    float* Wtl1 = Wt2 + 128 * 128;
    float* Wtl2 = Wtl1 + 256 * 256;
    int*   off  = (int*)(Wtl2 + 128 * 256);
    int*   cur  = off + SCAN_N + 1;
    int*   idx  = cur + SCAN_N;
    int*   bsum = idx + 2 * EE;

    // weights transpose (independent of CSR chain)
    k_transpose_all<<<512, 256, 0, stream>>>(W1, W2, Wl1, Wl2, Wt1, Wt2, Wtl1, Wtl2);

    // CSR build: count -> scan(3) -> fill
    hipMemsetAsync(off, 0, (SCAN_N + 1) * sizeof(int), stream);
    k_count<<<EE / 256, 256, 0, stream>>>(ei, off);
    k_scan1<<<SCAN_BLOCKS, 256, 0, stream>>>(off, bsum);
    k_scan2<<<1, 256, 0, stream>>>(bsum);
    k_scan3<<<SCAN_BLOCKS, 256, 0, stream>>>(off, bsum, cur);
    k_fill<<<EE / 256, 256, 0, stream>>>(ei, cur, idx);

    // gather: h = x + segment_sum (no float atomics)
    k_gather<<<SCAN_N / 8, 256, 0, stream>>>((const float4*)x, off, idx, (float4*)h1, (float4*)h2);

    // GIN branches -> cat
    int nb128 = (NN + 127) / 128;
    k_branch<<<dim3(nb128, 2), 256, 0, stream>>>(h1, h2, Wt1, Wt2,
                                                 b1, b2, g1, g2, bt1, bt2, cat);

    // merge MLP
    int nb64 = (NN + 63) / 64;
    k_mlp1<<<nb64, 256, 0, stream>>>(cat, Wtl1, bl1, mid);
    k_mlp2<<<nb128, 256, 0, stream>>>(mid, Wtl2, bl2, out);
}

// Round 7
// 1120.066 us; speedup vs baseline: 1.1931x; 1.1931x over previous
//
#include <hip/hip_runtime.h>
#include <hip/hip_bf16.h>

#define NN 100000
#define EE 1600000
#define DD 128
#define SCAN_N (2 * NN)            // concatenated degree array: [dst-counts | src-counts]
#define SCAN_BLOCKS ((SCAN_N + 1023) / 1024)   // 196

// ---------------------------------------------------------------- transpose
__global__ __launch_bounds__(256) void k_transpose_all(const float* __restrict__ W1,
                                                       const float* __restrict__ W2,
                                                       const float* __restrict__ Wl1,
                                                       const float* __restrict__ Wl2,
                                                       float* __restrict__ Wt1,
                                                       float* __restrict__ Wt2,
                                                       float* __restrict__ Wtl1,
                                                       float* __restrict__ Wtl2) {
    int tid = blockIdx.x * 256 + threadIdx.x;   // 131072 threads total
    const float* in;
    float* out;
    int C, R, off;
    if (tid < 16384)      { in = W1;  out = Wt1;  R = 128; C = 128; off = 0; }
    else if (tid < 32768) { in = W2;  out = Wt2;  R = 128; C = 128; off = 16384; }
    else if (tid < 98304) { in = Wl1; out = Wtl1; R = 256; C = 256; off = 32768; }
    else                  { in = Wl2; out = Wtl2; R = 128; C = 256; off = 98304; }
    int i = tid - off;
    int r = i / C, c = i - r * C;
    out[c * R + r] = in[i];
}

// ---------------------------------------------------------------- CSR build
__global__ __launch_bounds__(256) void k_count(const int* __restrict__ ei,
                                               int* __restrict__ off) {
    int e = blockIdx.x * 256 + threadIdx.x;     // EE threads exactly
    int s = ei[e];
    int d = ei[EE + e];
    atomicAdd(&off[d], 1);
    atomicAdd(&off[NN + s], 1);
}

__global__ __launch_bounds__(256) void k_scan1(int* __restrict__ off,
                                               int* __restrict__ bsum) {
    __shared__ int s[256];
    int t = threadIdx.x;
    int base = blockIdx.x * 1024 + t * 4;
    int v[4];
    #pragma unroll
    for (int i = 0; i < 4; ++i) {
        int g = base + i;
        v[i] = (g < SCAN_N) ? off[g] : 0;
    }
    int local = v[0] + v[1] + v[2] + v[3];
    s[t] = local;
    __syncthreads();
    #pragma unroll
    for (int o = 1; o < 256; o <<= 1) {
        int add = (t >= o) ? s[t - o] : 0;
        __syncthreads();
        s[t] += add;
        __syncthreads();
    }
    int run = s[t] - local;
    #pragma unroll
    for (int i = 0; i < 4; ++i) {
        int g = base + i;
        if (g < SCAN_N) off[g] = run;
        run += v[i];
    }
    if (t == 0) bsum[blockIdx.x] = s[255];
}

__global__ __launch_bounds__(256) void k_scan2(int* __restrict__ bsum) {
    __shared__ int s[256];
    int t = threadIdx.x;
    int local = (t < SCAN_BLOCKS) ? bsum[t] : 0;
    s[t] = local;
    __syncthreads();
    #pragma unroll
    for (int o = 1; o < 256; o <<= 1) {
        int add = (t >= o) ? s[t - o] : 0;
        __syncthreads();
        s[t] += add;
        __syncthreads();
    }
    if (t < SCAN_BLOCKS) bsum[t] = s[t] - local;
}

__global__ __launch_bounds__(256) void k_scan3(int* __restrict__ off,
                                               const int* __restrict__ bsum,
                                               int* __restrict__ cur) {
    int t = threadIdx.x;
    int base = blockIdx.x * 1024 + t * 4;
    int add = bsum[blockIdx.x];
    #pragma unroll
    for (int i = 0; i < 4; ++i) {
        int g = base + i;
        if (g < SCAN_N) {
            int v = off[g] + add;
            off[g] = v;
            cur[g] = v;
        }
    }
    if (blockIdx.x == 0 && t == 0) off[SCAN_N] = 2 * EE;
}

__global__ __launch_bounds__(256) void k_fill(const int* __restrict__ ei,
                                              int* __restrict__ cur,
                                              int* __restrict__ idx) {
    int e = blockIdx.x * 256 + threadIdx.x;
    int s = ei[e];
    int d = ei[EE + e];
    int p1 = atomicAdd(&cur[d], 1);
    idx[p1] = s;
    int p2 = atomicAdd(&cur[NN + s], 1);
    idx[p2] = d;
}

// ---------------------------------------------------------------- gather
// One 32-lane group per (node, branch); lane c owns float4 column c.
// Unrolled by 4: 4 independent row-loads in flight (was a serial latency
// chain of ~deg x L2-latency).
__global__ __launch_bounds__(256) void k_gather(const float4* __restrict__ x4,
                                                const int* __restrict__ off,
                                                const int* __restrict__ idx,
                                                float4* __restrict__ h1,
                                                float4* __restrict__ h2) {
    int t = threadIdx.x;
    int g = blockIdx.x * 8 + (t >> 5);
    int c = t & 31;
    int n = (g < NN) ? g : g - NN;
    int o0 = off[g], o1 = off[g + 1];
    float4 acc = x4[n * 32 + c];                // + x (GIN eps=0 self term)
    int j = o0;
    for (; j + 4 <= o1; j += 4) {
        int n0 = idx[j], n1 = idx[j + 1], n2 = idx[j + 2], n3 = idx[j + 3];
        float4 v0 = x4[n0 * 32 + c];
        float4 v1 = x4[n1 * 32 + c];
        float4 v2 = x4[n2 * 32 + c];
        float4 v3 = x4[n3 * 32 + c];
        acc.x += v0.x + v1.x + v2.x + v3.x;
        acc.y += v0.y + v1.y + v2.y + v3.y;
        acc.z += v0.z + v1.z + v2.z + v3.z;
        acc.w += v0.w + v1.w + v2.w + v3.w;
    }
    for (; j < o1; ++j) {
        int nbr = idx[j];
        float4 v = x4[nbr * 32 + c];
        acc.x += v.x; acc.y += v.y; acc.z += v.z; acc.w += v.w;
    }
    float4* hout = (g < NN) ? h1 : h2;
    hout[n * 32 + c] = acc;
}

// ---------------------------------------------------------------- branch
// BM=128 BN=128 BK=32. LDS = hsT[32][132] + wst[32][132] = 33.8KB -> 4
// blocks/CU (was 136KB -> 1 block/CU, the round-3 bottleneck). A staged
// TRANSPOSED so the inner loop is 2x ds_read_b128 per operand. Epilogue:
// +bias, LN (shfl over 16 lanes), ReLU, residual (h re-read from global,
// L3-hit), write cat columns.
__global__ __launch_bounds__(256, 4) void k_branch(const float* __restrict__ h1,
                                                   const float* __restrict__ h2,
                                                   const float* __restrict__ Wt1,
                                                   const float* __restrict__ Wt2,
                                                   const float* __restrict__ bias1,
                                                   const float* __restrict__ bias2,
                                                   const float* __restrict__ gam1,
                                                   const float* __restrict__ gam2,
                                                   const float* __restrict__ beta1,
                                                   const float* __restrict__ beta2,
                                                   float* __restrict__ cat) {
    const int br = blockIdx.y;
    const float* h    = br ? h2    : h1;
    const float* Wt   = br ? Wt2   : Wt1;
    const float* bias = br ? bias2 : bias1;
    const float* gam  = br ? gam2  : gam1;
    const float* beta = br ? beta2 : beta1;
    const int colOff  = br ? 128 : 0;

    __shared__ float hsT[32 * 132];
    __shared__ float wst[32 * 132];
    int t = threadIdx.x;
    int m0 = blockIdx.x * 128;
    int my = t >> 4, tx = t & 15, n0 = tx * 8;

    float acc[8][8];
    #pragma unroll
    for (int i = 0; i < 8; ++i)
        #pragma unroll
        for (int j = 0; j < 8; ++j) acc[i][j] = 0.f;

    for (int k0 = 0; k0 < 128; k0 += 32) {
        __syncthreads();
        #pragma unroll
        for (int it = 0; it < 4; ++it) {        // A: 128 rows x 8 f4, transpose
            int f = it * 256 + t;
            int row = f >> 3, q = f & 7;
            int node = m0 + row;
            float4 v = make_float4(0.f, 0.f, 0.f, 0.f);
            if (node < NN) v = ((const float4*)h)[node * 32 + (k0 >> 2) + q];
            hsT[(q * 4 + 0) * 132 + row] = v.x;
            hsT[(q * 4 + 1) * 132 + row] = v.y;
            hsT[(q * 4 + 2) * 132 + row] = v.z;
            hsT[(q * 4 + 3) * 132 + row] = v.w;
        }
        #pragma unroll
        for (int it = 0; it < 4; ++it) {        // B: 32 k x 32 f4
            int f = it * 256 + t;
            int kl = f >> 5, n4 = f & 31;
            *(float4*)&wst[kl * 132 + n4 * 4] = ((const float4*)Wt)[(k0 + kl) * 32 + n4];
        }
        __syncthreads();
        #pragma unroll 4
        for (int kl = 0; kl < 32; ++kl) {
            float4 a0 = *(const float4*)&hsT[kl * 132 + my * 8];
            float4 a1 = *(const float4*)&hsT[kl * 132 + my * 8 + 4];
            float4 b0 = *(const float4*)&wst[kl * 132 + n0];
            float4 b1 = *(const float4*)&wst[kl * 132 + n0 + 4];
            float aa[8] = {a0.x, a0.y, a0.z, a0.w, a1.x, a1.y, a1.z, a1.w};
            float bb[8] = {b0.x, b0.y, b0.z, b0.w, b1.x, b1.y, b1.z, b1.w};
            #pragma unroll
            for (int i = 0; i < 8; ++i)
                #pragma unroll
                for (int j = 0; j < 8; ++j) acc[i][j] += aa[i] * bb[j];
        }
    }

    float breg[8], greg[8], btreg[8];
    #pragma unroll
    for (int j = 0; j < 8; ++j) {
        breg[j]  = bias[n0 + j];
        greg[j]  = gam[n0 + j];
        btreg[j] = beta[n0 + j];
    }
    #pragma unroll
    for (int i = 0; i < 8; ++i) {
        float s = 0.f, q = 0.f;
        #pragma unroll
        for (int j = 0; j < 8; ++j) {
            float v = acc[i][j] + breg[j];
            acc[i][j] = v;
            s += v;
            q += v * v;
        }
        #pragma unroll
        for (int o = 1; o < 16; o <<= 1) {
            s += __shfl_xor(s, o);
            q += __shfl_xor(q, o);
        }
        float mu  = s * (1.f / 128.f);
        float var = q * (1.f / 128.f) - mu * mu;
        float rs  = rsqrtf(var + 1e-5f);
        int node = m0 + my * 8 + i;
        if (node < NN) {
            const float4* hrow = (const float4*)&h[(size_t)node * 128];
            float4 r0 = hrow[tx * 2];
            float4 r1 = hrow[tx * 2 + 1];
            float hres[8] = {r0.x, r0.y, r0.z, r0.w, r1.x, r1.y, r1.z, r1.w};
            float o_[8];
            #pragma unroll
            for (int j = 0; j < 8; ++j) {
                float y = (acc[i][j] - mu) * rs * greg[j] + btreg[j];
                o_[j] = hres[j] + fmaxf(y, 0.f);   // ret = h + relu(LN)
            }
            float4* cp = (float4*)&cat[(size_t)node * 256 + colOff + n0];
            cp[0] = make_float4(o_[0], o_[1], o_[2], o_[3]);
            cp[1] = make_float4(o_[4], o_[5], o_[6], o_[7]);
        }
    }
}

// ---------------------------------------------------------------- mlp1
// mid = relu(cat @ Wl1^T + bl1). BM=128, BN=128 (blockIdx.y = n-half),
// K=256 in 8 chunks of 32. Same 33.8KB LDS / 4 blocks/CU structure.
__global__ __launch_bounds__(256, 4) void k_mlp1(const float* __restrict__ cat,
                                                 const float* __restrict__ Wt,
                                                 const float* __restrict__ bias,
                                                 float* __restrict__ mid) {
    __shared__ float hsT[32 * 132];
    __shared__ float wst[32 * 132];
    int t = threadIdx.x;
    int m0 = blockIdx.x * 128;
    int nbase = blockIdx.y * 128;
    int my = t >> 4, tx = t & 15, n0 = tx * 8;

    float acc[8][8];
    #pragma unroll
    for (int i = 0; i < 8; ++i)
        #pragma unroll
        for (int j = 0; j < 8; ++j) acc[i][j] = 0.f;

    for (int k0 = 0; k0 < 256; k0 += 32) {
        __syncthreads();
        #pragma unroll
        for (int it = 0; it < 4; ++it) {        // A: cat rows (64 f4/row)
            int f = it * 256 + t;
            int row = f >> 3, q = f & 7;
            int node = m0 + row;
            float4 v = make_float4(0.f, 0.f, 0.f, 0.f);
            if (node < NN) v = ((const float4*)cat)[(size_t)node * 64 + (k0 >> 2) + q];
            hsT[(q * 4 + 0) * 132 + row] = v.x;
            hsT[(q * 4 + 1) * 132 + row] = v.y;
            hsT[(q * 4 + 2) * 132 + row] = v.z;
            hsT[(q * 4 + 3) * 132 + row] = v.w;
        }
        #pragma unroll
        for (int it = 0; it < 4; ++it) {        // B: Wtl1 [k][n], 64 f4/row
            int f = it * 256 + t;
            int kl = f >> 5, n4 = f & 31;
            *(float4*)&wst[kl * 132 + n4 * 4] =
                ((const float4*)Wt)[(k0 + kl) * 64 + blockIdx.y * 32 + n4];
        }
        __syncthreads();
        #pragma unroll 4
        for (int kl = 0; kl < 32; ++kl) {
            float4 a0 = *(const float4*)&hsT[kl * 132 + my * 8];
            float4 a1 = *(const float4*)&hsT[kl * 132 + my * 8 + 4];
            float4 b0 = *(const float4*)&wst[kl * 132 + n0];
            float4 b1 = *(const float4*)&wst[kl * 132 + n0 + 4];
            float aa[8] = {a0.x, a0.y, a0.z, a0.w, a1.x, a1.y, a1.z, a1.w};
            float bb[8] = {b0.x, b0.y, b0.z, b0.w, b1.x, b1.y, b1.z, b1.w};
            #pragma unroll
            for (int i = 0; i < 8; ++i)
                #pragma unroll
                for (int j = 0; j < 8; ++j) acc[i][j] += aa[i] * bb[j];
        }
    }

    float breg[8];
    #pragma unroll
    for (int j = 0; j < 8; ++j) breg[j] = bias[nbase + n0 + j];
    #pragma unroll
    for (int i = 0; i < 8; ++i) {
        int node = m0 + my * 8 + i;
        if (node < NN) {
            float o_[8];
            #pragma unroll
            for (int j = 0; j < 8; ++j) o_[j] = fmaxf(acc[i][j] + breg[j], 0.f);
            float4* mp = (float4*)&mid[(size_t)node * 256 + nbase + n0];
            mp[0] = make_float4(o_[0], o_[1], o_[2], o_[3]);
            mp[1] = make_float4(o_[4], o_[5], o_[6], o_[7]);
        }
    }
}

// ---------------------------------------------------------------- mlp2
// out = relu(mid @ Wl2^T + bl2). BM=128, BN=128, K=256 in 8 chunks.
__global__ __launch_bounds__(256, 4) void k_mlp2(const float* __restrict__ mid,
                                                 const float* __restrict__ Wt,
                                                 const float* __restrict__ bias,
                                                 float* __restrict__ out) {
    __shared__ float hsT[32 * 132];
    __shared__ float wst[32 * 132];
    int t = threadIdx.x;
    int m0 = blockIdx.x * 128;
    int my = t >> 4, tx = t & 15, n0 = tx * 8;

    float acc[8][8];
    #pragma unroll
    for (int i = 0; i < 8; ++i)
        #pragma unroll
        for (int j = 0; j < 8; ++j) acc[i][j] = 0.f;

    for (int k0 = 0; k0 < 256; k0 += 32) {
        __syncthreads();
        #pragma unroll
        for (int it = 0; it < 4; ++it) {        // A: mid rows (64 f4/row)
            int f = it * 256 + t;
            int row = f >> 3, q = f & 7;
            int node = m0 + row;
            float4 v = make_float4(0.f, 0.f, 0.f, 0.f);
            if (node < NN) v = ((const float4*)mid)[(size_t)node * 64 + (k0 >> 2) + q];
            hsT[(q * 4 + 0) * 132 + row] = v.x;
            hsT[(q * 4 + 1) * 132 + row] = v.y;
            hsT[(q * 4 + 2) * 132 + row] = v.z;
            hsT[(q * 4 + 3) * 132 + row] = v.w;
        }
        #pragma unroll
        for (int it = 0; it < 4; ++it) {        // B: Wtl2 [k][n], 32 f4/row
            int f = it * 256 + t;
            int kl = f >> 5, n4 = f & 31;
            *(float4*)&wst[kl * 132 + n4 * 4] = ((const float4*)Wt)[(k0 + kl) * 32 + n4];
        }
        __syncthreads();
        #pragma unroll 4
        for (int kl = 0; kl < 32; ++kl) {
            float4 a0 = *(const float4*)&hsT[kl * 132 + my * 8];
            float4 a1 = *(const float4*)&hsT[kl * 132 + my * 8 + 4];
            float4 b0 = *(const float4*)&wst[kl * 132 + n0];
            float4 b1 = *(const float4*)&wst[kl * 132 + n0 + 4];
            float aa[8] = {a0.x, a0.y, a0.z, a0.w, a1.x, a1.y, a1.z, a1.w};
            float bb[8] = {b0.x, b0.y, b0.z, b0.w, b1.x, b1.y, b1.z, b1.w};
            #pragma unroll
            for (int i = 0; i < 8; ++i)
                #pragma unroll
                for (int j = 0; j < 8; ++j) acc[i][j] += aa[i] * bb[j];
        }
    }

    float breg[8];
    #pragma unroll
    for (int j = 0; j < 8; ++j) breg[j] = bias[n0 + j];
    #pragma unroll
    for (int i = 0; i < 8; ++i) {
        int node = m0 + my * 8 + i;
        if (node < NN) {
            float o_[8];
            #pragma unroll
            for (int j = 0; j < 8; ++j) o_[j] = fmaxf(acc[i][j] + breg[j], 0.f);
            float4* op = (float4*)&out[(size_t)node * 128 + n0];
            op[0] = make_float4(o_[0], o_[1], o_[2], o_[3]);
            op[1] = make_float4(o_[4], o_[5], o_[6], o_[7]);
        }
    }
}

// ---------------------------------------------------------------- launch
extern "C" void kernel_launch(void* const* d_in, const int* in_sizes, int n_in,
                              void* d_out, int out_size, void* d_ws, size_t ws_size,
                              hipStream_t stream) {
    const float* x   = (const float*)d_in[0];
    const int*   ei  = (const int*)d_in[1];
    const float* W1  = (const float*)d_in[2];
    const float* b1  = (const float*)d_in[3];
    const float* g1  = (const float*)d_in[4];
    const float* bt1 = (const float*)d_in[5];
    const float* W2  = (const float*)d_in[6];
    const float* b2  = (const float*)d_in[7];
    const float* g2  = (const float*)d_in[8];
    const float* bt2 = (const float*)d_in[9];
    const float* Wl1 = (const float*)d_in[10];
    const float* bl1 = (const float*)d_in[11];
    const float* Wl2 = (const float*)d_in[12];
    const float* bl2 = (const float*)d_in[13];
    float* out = (float*)d_out;

    float* ws   = (float*)d_ws;
    float* h1   = ws;
    float* h2   = ws + (size_t)NN * DD;
    float* mid  = ws;                           // reuse h region after branches
    float* cat  = ws + (size_t)2 * NN * DD;
    float* Wt1  = ws + (size_t)4 * NN * DD;
    float* Wt2  = Wt1 + 128 * 128;
    float* Wtl1 = Wt2 + 128 * 128;
    float* Wtl2 = Wtl1 + 256 * 256;
    int*   off  = (int*)(Wtl2 + 128 * 256);
    int*   cur  = off + SCAN_N + 1;
    int*   idx  = cur + SCAN_N;
    int*   bsum = idx + 2 * EE;

    k_transpose_all<<<512, 256, 0, stream>>>(W1, W2, Wl1, Wl2, Wt1, Wt2, Wtl1, Wtl2);

    hipMemsetAsync(off, 0, (SCAN_N + 1) * sizeof(int), stream);
    k_count<<<EE / 256, 256, 0, stream>>>(ei, off);
    k_scan1<<<SCAN_BLOCKS, 256, 0, stream>>>(off, bsum);
    k_scan2<<<1, 256, 0, stream>>>(bsum);
    k_scan3<<<SCAN_BLOCKS, 256, 0, stream>>>(off, bsum, cur);
    k_fill<<<EE / 256, 256, 0, stream>>>(ei, cur, idx);

    k_gather<<<SCAN_N / 8, 256, 0, stream>>>((const float4*)x, off, idx,
                                             (float4*)h1, (float4*)h2);

    int nb128 = (NN + 127) / 128;
    k_branch<<<dim3(nb128, 2), 256, 0, stream>>>(h1, h2, Wt1, Wt2,
                                                 b1, b2, g1, g2, bt1, bt2, cat);
    k_mlp1<<<dim3(nb128, 2), 256, 0, stream>>>(cat, Wtl1, bl1, mid);
    k_mlp2<<<nb128, 256, 0, stream>>>(mid, Wtl2, bl2, out);
}

// Round 9
// 980.490 us; speedup vs baseline: 1.3629x; 1.1424x over previous
//
#include <hip/hip_runtime.h>
#include <hip/hip_bf16.h>

#define NN 100000
#define EE 1600000
#define DD 128
#define SCAN_N (2 * NN)            // concatenated degree array: [dst-counts | src-counts]
#define SCAN_BLOCKS ((SCAN_N + 1023) / 1024)   // 196
#define FILL_PASSES 4
#define FILL_RANGE (NN / FILL_PASSES)          // 25000

// ---------------------------------------------------------------- transpose
__global__ __launch_bounds__(256) void k_transpose_all(const float* __restrict__ W1,
                                                       const float* __restrict__ W2,
                                                       const float* __restrict__ Wl1,
                                                       const float* __restrict__ Wl2,
                                                       float* __restrict__ Wt1,
                                                       float* __restrict__ Wt2,
                                                       float* __restrict__ Wtl1,
                                                       float* __restrict__ Wtl2) {
    int tid = blockIdx.x * 256 + threadIdx.x;   // 131072 threads total
    const float* in;
    float* out;
    int C, R, off;
    if (tid < 16384)      { in = W1;  out = Wt1;  R = 128; C = 128; off = 0; }
    else if (tid < 32768) { in = W2;  out = Wt2;  R = 128; C = 128; off = 16384; }
    else if (tid < 98304) { in = Wl1; out = Wtl1; R = 256; C = 256; off = 32768; }
    else                  { in = Wl2; out = Wtl2; R = 128; C = 256; off = 98304; }
    int i = tid - off;
    int r = i / C, c = i - r * C;
    out[c * R + r] = in[i];
}

// ---------------------------------------------------------------- CSR build
__global__ __launch_bounds__(256) void k_count(const int* __restrict__ ei,
                                               int* __restrict__ off) {
    int e = blockIdx.x * 256 + threadIdx.x;     // EE threads exactly
    int s = ei[e];
    int d = ei[EE + e];
    atomicAdd(&off[d], 1);
    atomicAdd(&off[NN + s], 1);
}

__global__ __launch_bounds__(256) void k_scan1(int* __restrict__ off,
                                               int* __restrict__ bsum) {
    __shared__ int s[256];
    int t = threadIdx.x;
    int base = blockIdx.x * 1024 + t * 4;
    int v[4];
    #pragma unroll
    for (int i = 0; i < 4; ++i) {
        int g = base + i;
        v[i] = (g < SCAN_N) ? off[g] : 0;
    }
    int local = v[0] + v[1] + v[2] + v[3];
    s[t] = local;
    __syncthreads();
    #pragma unroll
    for (int o = 1; o < 256; o <<= 1) {
        int add = (t >= o) ? s[t - o] : 0;
        __syncthreads();
        s[t] += add;
        __syncthreads();
    }
    int run = s[t] - local;
    #pragma unroll
    for (int i = 0; i < 4; ++i) {
        int g = base + i;
        if (g < SCAN_N) off[g] = run;
        run += v[i];
    }
    if (t == 0) bsum[blockIdx.x] = s[255];
}

__global__ __launch_bounds__(256) void k_scan2(int* __restrict__ bsum) {
    __shared__ int s[256];
    int t = threadIdx.x;
    int local = (t < SCAN_BLOCKS) ? bsum[t] : 0;
    s[t] = local;
    __syncthreads();
    #pragma unroll
    for (int o = 1; o < 256; o <<= 1) {
        int add = (t >= o) ? s[t - o] : 0;
        __syncthreads();
        s[t] += add;
        __syncthreads();
    }
    if (t < SCAN_BLOCKS) bsum[t] = s[t] - local;
}

__global__ __launch_bounds__(256) void k_scan3(int* __restrict__ off,
                                               const int* __restrict__ bsum,
                                               int* __restrict__ cur) {
    int t = threadIdx.x;
    int base = blockIdx.x * 1024 + t * 4;
    int add = bsum[blockIdx.x];
    #pragma unroll
    for (int i = 0; i < 4; ++i) {
        int g = base + i;
        if (g < SCAN_N) {
            int v = off[g] + add;
            off[g] = v;
            cur[g] = v;
        }
    }
    if (blockIdx.x == 0 && t == 0) off[SCAN_N] = 2 * EE;
}

// fill, v2: fixes the 16x write amplification seen in round 7 (WRITE_SIZE
// 208MB for a 12.8MB idx array; each random 4B write evicted a 64B line).
// Grid x8: blocks 8w..8w+7 share the 256-edge window w; block (b&7) only
// writes nodes with (node>>3)&7 == (b&7). With round-robin blockIdx->XCD
// dispatch, each XCD's L2 then holds only its owned 1.6MB slice of idx ->
// lines fill before eviction. Exactly-once per edge-direction holds by
// construction, independent of the actual XCD mapping (only speed depends
// on it). 4 range-passes (register loop, no re-reads) shrink the active
// region further (~0.8MB/phase).
__global__ __launch_bounds__(256) void k_fill(const int* __restrict__ ei,
                                              int* __restrict__ cur,
                                              int* __restrict__ idx) {
    int b = blockIdx.x;
    int w = b >> 3, myk = b & 7;
    int e = w * 256 + threadIdx.x;
    int s = ei[e];
    int d = ei[EE + e];
    bool ownD = (((d >> 3) & 7) == myk);
    bool ownS = (((s >> 3) & 7) == myk);
    #pragma unroll
    for (int p = 0; p < FILL_PASSES; ++p) {
        if (ownD && d >= p * FILL_RANGE && d < (p + 1) * FILL_RANGE) {
            int p1 = atomicAdd(&cur[d], 1);
            idx[p1] = s;
        }
        if (ownS && s >= p * FILL_RANGE && s < (p + 1) * FILL_RANGE) {
            int p2 = atomicAdd(&cur[NN + s], 1);
            idx[p2] = d;
        }
        __syncthreads();
    }
}

// ---------------------------------------------------------------- gather
// One 32-lane group per (node, branch); lane c owns float4 column c.
// Unrolled by 4: 4 independent row-loads in flight (was a serial latency
// chain of ~deg x L2-latency).
__global__ __launch_bounds__(256) void k_gather(const float4* __restrict__ x4,
                                                const int* __restrict__ off,
                                                const int* __restrict__ idx,
                                                float4* __restrict__ h1,
                                                float4* __restrict__ h2) {
    int t = threadIdx.x;
    int g = blockIdx.x * 8 + (t >> 5);
    int c = t & 31;
    int n = (g < NN) ? g : g - NN;
    int o0 = off[g], o1 = off[g + 1];
    float4 acc = x4[n * 32 + c];                // + x (GIN eps=0 self term)
    int j = o0;
    for (; j + 4 <= o1; j += 4) {
        int n0 = idx[j], n1 = idx[j + 1], n2 = idx[j + 2], n3 = idx[j + 3];
        float4 v0 = x4[n0 * 32 + c];
        float4 v1 = x4[n1 * 32 + c];
        float4 v2 = x4[n2 * 32 + c];
        float4 v3 = x4[n3 * 32 + c];
        acc.x += v0.x + v1.x + v2.x + v3.x;
        acc.y += v0.y + v1.y + v2.y + v3.y;
        acc.z += v0.z + v1.z + v2.z + v3.z;
        acc.w += v0.w + v1.w + v2.w + v3.w;
    }
    for (; j < o1; ++j) {
        int nbr = idx[j];
        float4 v = x4[nbr * 32 + c];
        acc.x += v.x; acc.y += v.y; acc.z += v.z; acc.w += v.w;
    }
    float4* hout = (g < NN) ? h1 : h2;
    hout[n * 32 + c] = acc;
}

// ---------------------------------------------------------------- branch
// BM=128 BN=128 BK=32. LDS = 33.8KB -> 4 blocks/CU. Epilogue: +bias, LN
// (shfl over 16 lanes), ReLU, residual, write cat columns.
__global__ __launch_bounds__(256, 4) void k_branch(const float* __restrict__ h1,
                                                   const float* __restrict__ h2,
                                                   const float* __restrict__ Wt1,
                                                   const float* __restrict__ Wt2,
                                                   const float* __restrict__ bias1,
                                                   const float* __restrict__ bias2,
                                                   const float* __restrict__ gam1,
                                                   const float* __restrict__ gam2,
                                                   const float* __restrict__ beta1,
                                                   const float* __restrict__ beta2,
                                                   float* __restrict__ cat) {
    const int br = blockIdx.y;
    const float* h    = br ? h2    : h1;
    const float* Wt   = br ? Wt2   : Wt1;
    const float* bias = br ? bias2 : bias1;
    const float* gam  = br ? gam2  : gam1;
    const float* beta = br ? beta2 : beta1;
    const int colOff  = br ? 128 : 0;

    __shared__ float hsT[32 * 132];
    __shared__ float wst[32 * 132];
    int t = threadIdx.x;
    int m0 = blockIdx.x * 128;
    int my = t >> 4, tx = t & 15, n0 = tx * 8;

    float acc[8][8];
    #pragma unroll
    for (int i = 0; i < 8; ++i)
        #pragma unroll
        for (int j = 0; j < 8; ++j) acc[i][j] = 0.f;

    for (int k0 = 0; k0 < 128; k0 += 32) {
        __syncthreads();
        #pragma unroll
        for (int it = 0; it < 4; ++it) {        // A: 128 rows x 8 f4, transpose
            int f = it * 256 + t;
            int row = f >> 3, q = f & 7;
            int node = m0 + row;
            float4 v = make_float4(0.f, 0.f, 0.f, 0.f);
            if (node < NN) v = ((const float4*)h)[node * 32 + (k0 >> 2) + q];
            hsT[(q * 4 + 0) * 132 + row] = v.x;
            hsT[(q * 4 + 1) * 132 + row] = v.y;
            hsT[(q * 4 + 2) * 132 + row] = v.z;
            hsT[(q * 4 + 3) * 132 + row] = v.w;
        }
        #pragma unroll
        for (int it = 0; it < 4; ++it) {        // B: 32 k x 32 f4
            int f = it * 256 + t;
            int kl = f >> 5, n4 = f & 31;
            *(float4*)&wst[kl * 132 + n4 * 4] = ((const float4*)Wt)[(k0 + kl) * 32 + n4];
        }
        __syncthreads();
        #pragma unroll 4
        for (int kl = 0; kl < 32; ++kl) {
            float4 a0 = *(const float4*)&hsT[kl * 132 + my * 8];
            float4 a1 = *(const float4*)&hsT[kl * 132 + my * 8 + 4];
            float4 b0 = *(const float4*)&wst[kl * 132 + n0];
            float4 b1 = *(const float4*)&wst[kl * 132 + n0 + 4];
            float aa[8] = {a0.x, a0.y, a0.z, a0.w, a1.x, a1.y, a1.z, a1.w};
            float bb[8] = {b0.x, b0.y, b0.z, b0.w, b1.x, b1.y, b1.z, b1.w};
            #pragma unroll
            for (int i = 0; i < 8; ++i)
                #pragma unroll
                for (int j = 0; j < 8; ++j) acc[i][j] += aa[i] * bb[j];
        }
    }

    float breg[8], greg[8], btreg[8];
    #pragma unroll
    for (int j = 0; j < 8; ++j) {
        breg[j]  = bias[n0 + j];
        greg[j]  = gam[n0 + j];
        btreg[j] = beta[n0 + j];
    }
    #pragma unroll
    for (int i = 0; i < 8; ++i) {
        float s = 0.f, q = 0.f;
        #pragma unroll
        for (int j = 0; j < 8; ++j) {
            float v = acc[i][j] + breg[j];
            acc[i][j] = v;
            s += v;
            q += v * v;
        }
        #pragma unroll
        for (int o = 1; o < 16; o <<= 1) {
            s += __shfl_xor(s, o);
            q += __shfl_xor(q, o);
        }
        float mu  = s * (1.f / 128.f);
        float var = q * (1.f / 128.f) - mu * mu;
        float rs  = rsqrtf(var + 1e-5f);
        int node = m0 + my * 8 + i;
        if (node < NN) {
            const float4* hrow = (const float4*)&h[(size_t)node * 128];
            float4 r0 = hrow[tx * 2];
            float4 r1 = hrow[tx * 2 + 1];
            float hres[8] = {r0.x, r0.y, r0.z, r0.w, r1.x, r1.y, r1.z, r1.w};
            float o_[8];
            #pragma unroll
            for (int j = 0; j < 8; ++j) {
                float y = (acc[i][j] - mu) * rs * greg[j] + btreg[j];
                o_[j] = hres[j] + fmaxf(y, 0.f);   // ret = h + relu(LN)
            }
            float4* cp = (float4*)&cat[(size_t)node * 256 + colOff + n0];
            cp[0] = make_float4(o_[0], o_[1], o_[2], o_[3]);
            cp[1] = make_float4(o_[4], o_[5], o_[6], o_[7]);
        }
    }
}

// ---------------------------------------------------------------- mlp1
// mid = relu(cat @ Wl1^T + bl1). BM=128, BN=128 (blockIdx.y = n-half),
// K=256 in 8 chunks of 32.
__global__ __launch_bounds__(256, 4) void k_mlp1(const float* __restrict__ cat,
                                                 const float* __restrict__ Wt,
                                                 const float* __restrict__ bias,
                                                 float* __restrict__ mid) {
    __shared__ float hsT[32 * 132];
    __shared__ float wst[32 * 132];
    int t = threadIdx.x;
    int m0 = blockIdx.x * 128;
    int nbase = blockIdx.y * 128;
    int my = t >> 4, tx = t & 15, n0 = tx * 8;

    float acc[8][8];
    #pragma unroll
    for (int i = 0; i < 8; ++i)
        #pragma unroll
        for (int j = 0; j < 8; ++j) acc[i][j] = 0.f;

    for (int k0 = 0; k0 < 256; k0 += 32) {
        __syncthreads();
        #pragma unroll
        for (int it = 0; it < 4; ++it) {        // A: cat rows (64 f4/row)
            int f = it * 256 + t;
            int row = f >> 3, q = f & 7;
            int node = m0 + row;
            float4 v = make_float4(0.f, 0.f, 0.f, 0.f);
            if (node < NN) v = ((const float4*)cat)[(size_t)node * 64 + (k0 >> 2) + q];
            hsT[(q * 4 + 0) * 132 + row] = v.x;
            hsT[(q * 4 + 1) * 132 + row] = v.y;
            hsT[(q * 4 + 2) * 132 + row] = v.z;
            hsT[(q * 4 + 3) * 132 + row] = v.w;
        }
        #pragma unroll
        for (int it = 0; it < 4; ++it) {        // B: Wtl1 [k][n], 64 f4/row
            int f = it * 256 + t;
            int kl = f >> 5, n4 = f & 31;
            *(float4*)&wst[kl * 132 + n4 * 4] =
                ((const float4*)Wt)[(k0 + kl) * 64 + blockIdx.y * 32 + n4];
        }
        __syncthreads();
        #pragma unroll 4
        for (int kl = 0; kl < 32; ++kl) {
            float4 a0 = *(const float4*)&hsT[kl * 132 + my * 8];
            float4 a1 = *(const float4*)&hsT[kl * 132 + my * 8 + 4];
            float4 b0 = *(const float4*)&wst[kl * 132 + n0];
            float4 b1 = *(const float4*)&wst[kl * 132 + n0 + 4];
            float aa[8] = {a0.x, a0.y, a0.z, a0.w, a1.x, a1.y, a1.z, a1.w};
            float bb[8] = {b0.x, b0.y, b0.z, b0.w, b1.x, b1.y, b1.z, b1.w};
            #pragma unroll
            for (int i = 0; i < 8; ++i)
                #pragma unroll
                for (int j = 0; j < 8; ++j) acc[i][j] += aa[i] * bb[j];
        }
    }

    float breg[8];
    #pragma unroll
    for (int j = 0; j < 8; ++j) breg[j] = bias[nbase + n0 + j];
    #pragma unroll
    for (int i = 0; i < 8; ++i) {
        int node = m0 + my * 8 + i;
        if (node < NN) {
            float o_[8];
            #pragma unroll
            for (int j = 0; j < 8; ++j) o_[j] = fmaxf(acc[i][j] + breg[j], 0.f);
            float4* mp = (float4*)&mid[(size_t)node * 256 + nbase + n0];
            mp[0] = make_float4(o_[0], o_[1], o_[2], o_[3]);
            mp[1] = make_float4(o_[4], o_[5], o_[6], o_[7]);
        }
    }
}

// ---------------------------------------------------------------- mlp2
// out = relu(mid @ Wl2^T + bl2). BM=128, BN=128, K=256 in 8 chunks.
__global__ __launch_bounds__(256, 4) void k_mlp2(const float* __restrict__ mid,
                                                 const float* __restrict__ Wt,
                                                 const float* __restrict__ bias,
                                                 float* __restrict__ out) {
    __shared__ float hsT[32 * 132];
    __shared__ float wst[32 * 132];
    int t = threadIdx.x;
    int m0 = blockIdx.x * 128;
    int my = t >> 4, tx = t & 15, n0 = tx * 8;

    float acc[8][8];
    #pragma unroll
    for (int i = 0; i < 8; ++i)
        #pragma unroll
        for (int j = 0; j < 8; ++j) acc[i][j] = 0.f;

    for (int k0 = 0; k0 < 256; k0 += 32) {
        __syncthreads();
        #pragma unroll
        for (int it = 0; it < 4; ++it) {        // A: mid rows (64 f4/row)
            int f = it * 256 + t;
            int row = f >> 3, q = f & 7;
            int node = m0 + row;
            float4 v = make_float4(0.f, 0.f, 0.f, 0.f);
            if (node < NN) v = ((const float4*)mid)[(size_t)node * 64 + (k0 >> 2) + q];
            hsT[(q * 4 + 0) * 132 + row] = v.x;
            hsT[(q * 4 + 1) * 132 + row] = v.y;
            hsT[(q * 4 + 2) * 132 + row] = v.z;
            hsT[(q * 4 + 3) * 132 + row] = v.w;
        }
        #pragma unroll
        for (int it = 0; it < 4; ++it) {        // B: Wtl2 [k][n], 32 f4/row
            int f = it * 256 + t;
            int kl = f >> 5, n4 = f & 31;
            *(float4*)&wst[kl * 132 + n4 * 4] = ((const float4*)Wt)[(k0 + kl) * 32 + n4];
        }
        __syncthreads();
        #pragma unroll 4
        for (int kl = 0; kl < 32; ++kl) {
            float4 a0 = *(const float4*)&hsT[kl * 132 + my * 8];
            float4 a1 = *(const float4*)&hsT[kl * 132 + my * 8 + 4];
            float4 b0 = *(const float4*)&wst[kl * 132 + n0];
            float4 b1 = *(const float4*)&wst[kl * 132 + n0 + 4];
            float aa[8] = {a0.x, a0.y, a0.z, a0.w, a1.x, a1.y, a1.z, a1.w};
            float bb[8] = {b0.x, b0.y, b0.z, b0.w, b1.x, b1.y, b1.z, b1.w};
            #pragma unroll
            for (int i = 0; i < 8; ++i)
                #pragma unroll
                for (int j = 0; j < 8; ++j) acc[i][j] += aa[i] * bb[j];
        }
    }

    float breg[8];
    #pragma unroll
    for (int j = 0; j < 8; ++j) breg[j] = bias[n0 + j];
    #pragma unroll
    for (int i = 0; i < 8; ++i) {
        int node = m0 + my * 8 + i;
        if (node < NN) {
            float o_[8];
            #pragma unroll
            for (int j = 0; j < 8; ++j) o_[j] = fmaxf(acc[i][j] + breg[j], 0.f);
            float4* op = (float4*)&out[(size_t)node * 128 + n0];
            op[0] = make_float4(o_[0], o_[1], o_[2], o_[3]);
            op[1] = make_float4(o_[4], o_[5], o_[6], o_[7]);
        }
    }
}

// ---------------------------------------------------------------- launch
extern "C" void kernel_launch(void* const* d_in, const int* in_sizes, int n_in,
                              void* d_out, int out_size, void* d_ws, size_t ws_size,
                              hipStream_t stream) {
    const float* x   = (const float*)d_in[0];
    const int*   ei  = (const int*)d_in[1];
    const float* W1  = (const float*)d_in[2];
    const float* b1  = (const float*)d_in[3];
    const float* g1  = (const float*)d_in[4];
    const float* bt1 = (const float*)d_in[5];
    const float* W2  = (const float*)d_in[6];
    const float* b2  = (const float*)d_in[7];
    const float* g2  = (const float*)d_in[8];
    const float* bt2 = (const float*)d_in[9];
    const float* Wl1 = (const float*)d_in[10];
    const float* bl1 = (const float*)d_in[11];
    const float* Wl2 = (const float*)d_in[12];
    const float* bl2 = (const float*)d_in[13];
    float* out = (float*)d_out;

    float* ws   = (float*)d_ws;
    float* h1   = ws;
    float* h2   = ws + (size_t)NN * DD;
    float* mid  = ws;                           // reuse h region after branches
    float* cat  = ws + (size_t)2 * NN * DD;
    float* Wt1  = ws + (size_t)4 * NN * DD;
    float* Wt2  = Wt1 + 128 * 128;
    float* Wtl1 = Wt2 + 128 * 128;
    float* Wtl2 = Wtl1 + 256 * 256;
    int*   off  = (int*)(Wtl2 + 128 * 256);
    int*   cur  = off + SCAN_N + 1;
    int*   idx  = cur + SCAN_N;
    int*   bsum = idx + 2 * EE;

    k_transpose_all<<<512, 256, 0, stream>>>(W1, W2, Wl1, Wl2, Wt1, Wt2, Wtl1, Wtl2);

    hipMemsetAsync(off, 0, (SCAN_N + 1) * sizeof(int), stream);
    k_count<<<EE / 256, 256, 0, stream>>>(ei, off);
    k_scan1<<<SCAN_BLOCKS, 256, 0, stream>>>(off, bsum);
    k_scan2<<<1, 256, 0, stream>>>(bsum);
    k_scan3<<<SCAN_BLOCKS, 256, 0, stream>>>(off, bsum, cur);
    k_fill<<<(EE / 256) * 8, 256, 0, stream>>>(ei, cur, idx);

    k_gather<<<SCAN_N / 8, 256, 0, stream>>>((const float4*)x, off, idx,
                                             (float4*)h1, (float4*)h2);

    int nb128 = (NN + 127) / 128;
    k_branch<<<dim3(nb128, 2), 256, 0, stream>>>(h1, h2, Wt1, Wt2,
                                                 b1, b2, g1, g2, bt1, bt2, cat);
    k_mlp1<<<dim3(nb128, 2), 256, 0, stream>>>(cat, Wtl1, bl1, mid);
    k_mlp2<<<nb128, 256, 0, stream>>>(mid, Wtl2, bl2, out);
}

// Round 10
// 868.819 us; speedup vs baseline: 1.5381x; 1.1285x over previous
//
#include <hip/hip_runtime.h>
#include <hip/hip_bf16.h>

#define NN 100000
#define EE 1600000
#define DD 128
#define SCAN_N (2 * NN)
#define SCAN_BLOCKS ((SCAN_N + 1023) / 1024)   // 196
#define FILL_PASSES 4
#define FILL_RANGE (NN / FILL_PASSES)          // 25000

typedef unsigned short u16;
typedef __attribute__((ext_vector_type(8))) short short8v;
typedef __attribute__((ext_vector_type(4))) float f32x4;

__device__ inline void bf16split(float v, u16& hi, u16& lo) {
    __hip_bfloat16 h = __float2bfloat16(v);          // RNE
    hi = *reinterpret_cast<u16*>(&h);
    float r = v - __bfloat162float(h);
    __hip_bfloat16 l = __float2bfloat16(r);
    lo = *reinterpret_cast<u16*>(&l);
}

// ---------------------------------------------------------------- prep
// Wt1/Wt2: fp32 transpose (branch kernel path, unchanged).
// Wl1/Wl2: bf16 hi/lo split in NATIVE [n][k] layout (MFMA B-frag wants
// W rows k-contiguous -- no transpose needed).
__global__ __launch_bounds__(256) void k_prep(const float* __restrict__ W1,
                                              const float* __restrict__ W2,
                                              const float* __restrict__ Wl1,
                                              const float* __restrict__ Wl2,
                                              float* __restrict__ Wt1,
                                              float* __restrict__ Wt2,
                                              u16* __restrict__ Wl1hi,
                                              u16* __restrict__ Wl1lo,
                                              u16* __restrict__ Wl2hi,
                                              u16* __restrict__ Wl2lo) {
    int tid = blockIdx.x * 256 + threadIdx.x;   // 131072 threads
    if (tid < 16384) {
        int r = tid >> 7, c = tid & 127;
        Wt1[c * 128 + r] = W1[tid];
    } else if (tid < 32768) {
        int i = tid - 16384;
        int r = i >> 7, c = i & 127;
        Wt2[c * 128 + r] = W2[i];
    } else if (tid < 98304) {
        int i = tid - 32768;                    // 0..65535, Wl1 [256][256]
        bf16split(Wl1[i], Wl1hi[i], Wl1lo[i]);
    } else {
        int i = tid - 98304;                    // 0..32767, Wl2 [128][256]
        bf16split(Wl2[i], Wl2hi[i], Wl2lo[i]);
    }
}

// ---------------------------------------------------------------- CSR build
__global__ __launch_bounds__(256) void k_count(const int* __restrict__ ei,
                                               int* __restrict__ off) {
    int e = blockIdx.x * 256 + threadIdx.x;
    int s = ei[e];
    int d = ei[EE + e];
    atomicAdd(&off[d], 1);
    atomicAdd(&off[NN + s], 1);
}

__global__ __launch_bounds__(256) void k_scan1(int* __restrict__ off,
                                               int* __restrict__ bsum) {
    __shared__ int s[256];
    int t = threadIdx.x;
    int base = blockIdx.x * 1024 + t * 4;
    int v[4];
    #pragma unroll
    for (int i = 0; i < 4; ++i) {
        int g = base + i;
        v[i] = (g < SCAN_N) ? off[g] : 0;
    }
    int local = v[0] + v[1] + v[2] + v[3];
    s[t] = local;
    __syncthreads();
    #pragma unroll
    for (int o = 1; o < 256; o <<= 1) {
        int add = (t >= o) ? s[t - o] : 0;
        __syncthreads();
        s[t] += add;
        __syncthreads();
    }
    int run = s[t] - local;
    #pragma unroll
    for (int i = 0; i < 4; ++i) {
        int g = base + i;
        if (g < SCAN_N) off[g] = run;
        run += v[i];
    }
    if (t == 0) bsum[blockIdx.x] = s[255];
}

__global__ __launch_bounds__(256) void k_scan2(int* __restrict__ bsum) {
    __shared__ int s[256];
    int t = threadIdx.x;
    int local = (t < SCAN_BLOCKS) ? bsum[t] : 0;
    s[t] = local;
    __syncthreads();
    #pragma unroll
    for (int o = 1; o < 256; o <<= 1) {
        int add = (t >= o) ? s[t - o] : 0;
        __syncthreads();
        s[t] += add;
        __syncthreads();
    }
    if (t < SCAN_BLOCKS) bsum[t] = s[t] - local;
}

__global__ __launch_bounds__(256) void k_scan3(int* __restrict__ off,
                                               const int* __restrict__ bsum,
                                               int* __restrict__ cur) {
    int t = threadIdx.x;
    int base = blockIdx.x * 1024 + t * 4;
    int add = bsum[blockIdx.x];
    #pragma unroll
    for (int i = 0; i < 4; ++i) {
        int g = base + i;
        if (g < SCAN_N) {
            int v = off[g] + add;
            off[g] = v;
            cur[g] = v;
        }
    }
    if (blockIdx.x == 0 && t == 0) off[SCAN_N] = 2 * EE;
}

__global__ __launch_bounds__(256) void k_fill(const int* __restrict__ ei,
                                              int* __restrict__ cur,
                                              int* __restrict__ idx) {
    int b = blockIdx.x;
    int w = b >> 3, myk = b & 7;
    int e = w * 256 + threadIdx.x;
    int s = ei[e];
    int d = ei[EE + e];
    bool ownD = (((d >> 3) & 7) == myk);
    bool ownS = (((s >> 3) & 7) == myk);
    #pragma unroll
    for (int p = 0; p < FILL_PASSES; ++p) {
        if (ownD && d >= p * FILL_RANGE && d < (p + 1) * FILL_RANGE) {
            int p1 = atomicAdd(&cur[d], 1);
            idx[p1] = s;
        }
        if (ownS && s >= p * FILL_RANGE && s < (p + 1) * FILL_RANGE) {
            int p2 = atomicAdd(&cur[NN + s], 1);
            idx[p2] = d;
        }
        __syncthreads();
    }
}

// ---------------------------------------------------------------- gather
__global__ __launch_bounds__(256) void k_gather(const float4* __restrict__ x4,
                                                const int* __restrict__ off,
                                                const int* __restrict__ idx,
                                                float4* __restrict__ h1,
                                                float4* __restrict__ h2) {
    int t = threadIdx.x;
    int g = blockIdx.x * 8 + (t >> 5);
    int c = t & 31;
    int n = (g < NN) ? g : g - NN;
    int o0 = off[g], o1 = off[g + 1];
    float4 acc = x4[n * 32 + c];
    int j = o0;
    for (; j + 4 <= o1; j += 4) {
        int n0 = idx[j], n1 = idx[j + 1], n2 = idx[j + 2], n3 = idx[j + 3];
        float4 v0 = x4[n0 * 32 + c];
        float4 v1 = x4[n1 * 32 + c];
        float4 v2 = x4[n2 * 32 + c];
        float4 v3 = x4[n3 * 32 + c];
        acc.x += v0.x + v1.x + v2.x + v3.x;
        acc.y += v0.y + v1.y + v2.y + v3.y;
        acc.z += v0.z + v1.z + v2.z + v3.z;
        acc.w += v0.w + v1.w + v2.w + v3.w;
    }
    for (; j < o1; ++j) {
        int nbr = idx[j];
        float4 v = x4[nbr * 32 + c];
        acc.x += v.x; acc.y += v.y; acc.z += v.z; acc.w += v.w;
    }
    float4* hout = (g < NN) ? h1 : h2;
    hout[n * 32 + c] = acc;
}

// ---------------------------------------------------------------- branch (fp32 vector, unchanged)
__global__ __launch_bounds__(256, 4) void k_branch(const float* __restrict__ h1,
                                                   const float* __restrict__ h2,
                                                   const float* __restrict__ Wt1,
                                                   const float* __restrict__ Wt2,
                                                   const float* __restrict__ bias1,
                                                   const float* __restrict__ bias2,
                                                   const float* __restrict__ gam1,
                                                   const float* __restrict__ gam2,
                                                   const float* __restrict__ beta1,
                                                   const float* __restrict__ beta2,
                                                   float* __restrict__ cat) {
    const int br = blockIdx.y;
    const float* h    = br ? h2    : h1;
    const float* Wt   = br ? Wt2   : Wt1;
    const float* bias = br ? bias2 : bias1;
    const float* gam  = br ? gam2  : gam1;
    const float* beta = br ? beta2 : beta1;
    const int colOff  = br ? 128 : 0;

    __shared__ float hsT[32 * 132];
    __shared__ float wst[32 * 132];
    int t = threadIdx.x;
    int m0 = blockIdx.x * 128;
    int my = t >> 4, tx = t & 15, n0 = tx * 8;

    float acc[8][8];
    #pragma unroll
    for (int i = 0; i < 8; ++i)
        #pragma unroll
        for (int j = 0; j < 8; ++j) acc[i][j] = 0.f;

    for (int k0 = 0; k0 < 128; k0 += 32) {
        __syncthreads();
        #pragma unroll
        for (int it = 0; it < 4; ++it) {
            int f = it * 256 + t;
            int row = f >> 3, q = f & 7;
            int node = m0 + row;
            float4 v = make_float4(0.f, 0.f, 0.f, 0.f);
            if (node < NN) v = ((const float4*)h)[node * 32 + (k0 >> 2) + q];
            hsT[(q * 4 + 0) * 132 + row] = v.x;
            hsT[(q * 4 + 1) * 132 + row] = v.y;
            hsT[(q * 4 + 2) * 132 + row] = v.z;
            hsT[(q * 4 + 3) * 132 + row] = v.w;
        }
        #pragma unroll
        for (int it = 0; it < 4; ++it) {
            int f = it * 256 + t;
            int kl = f >> 5, n4 = f & 31;
            *(float4*)&wst[kl * 132 + n4 * 4] = ((const float4*)Wt)[(k0 + kl) * 32 + n4];
        }
        __syncthreads();
        #pragma unroll 4
        for (int kl = 0; kl < 32; ++kl) {
            float4 a0 = *(const float4*)&hsT[kl * 132 + my * 8];
            float4 a1 = *(const float4*)&hsT[kl * 132 + my * 8 + 4];
            float4 b0 = *(const float4*)&wst[kl * 132 + n0];
            float4 b1 = *(const float4*)&wst[kl * 132 + n0 + 4];
            float aa[8] = {a0.x, a0.y, a0.z, a0.w, a1.x, a1.y, a1.z, a1.w};
            float bb[8] = {b0.x, b0.y, b0.z, b0.w, b1.x, b1.y, b1.z, b1.w};
            #pragma unroll
            for (int i = 0; i < 8; ++i)
                #pragma unroll
                for (int j = 0; j < 8; ++j) acc[i][j] += aa[i] * bb[j];
        }
    }

    float breg[8], greg[8], btreg[8];
    #pragma unroll
    for (int j = 0; j < 8; ++j) {
        breg[j]  = bias[n0 + j];
        greg[j]  = gam[n0 + j];
        btreg[j] = beta[n0 + j];
    }
    #pragma unroll
    for (int i = 0; i < 8; ++i) {
        float s = 0.f, q = 0.f;
        #pragma unroll
        for (int j = 0; j < 8; ++j) {
            float v = acc[i][j] + breg[j];
            acc[i][j] = v;
            s += v;
            q += v * v;
        }
        #pragma unroll
        for (int o = 1; o < 16; o <<= 1) {
            s += __shfl_xor(s, o);
            q += __shfl_xor(q, o);
        }
        float mu  = s * (1.f / 128.f);
        float var = q * (1.f / 128.f) - mu * mu;
        float rs  = rsqrtf(var + 1e-5f);
        int node = m0 + my * 8 + i;
        if (node < NN) {
            const float4* hrow = (const float4*)&h[(size_t)node * 128];
            float4 r0 = hrow[tx * 2];
            float4 r1 = hrow[tx * 2 + 1];
            float hres[8] = {r0.x, r0.y, r0.z, r0.w, r1.x, r1.y, r1.z, r1.w};
            float o_[8];
            #pragma unroll
            for (int j = 0; j < 8; ++j) {
                float y = (acc[i][j] - mu) * rs * greg[j] + btreg[j];
                o_[j] = hres[j] + fmaxf(y, 0.f);
            }
            float4* cp = (float4*)&cat[(size_t)node * 256 + colOff + n0];
            cp[0] = make_float4(o_[0], o_[1], o_[2], o_[3]);
            cp[1] = make_float4(o_[4], o_[5], o_[6], o_[7]);
        }
    }
}

// ---------------------------------------------------------------- MFMA MLP
// C = relu(A @ W^T + bias) via bf16 hi/lo split:
//   C ~= Ahi*Bhi + Ahi*Blo + Alo*Bhi  (fp32 MFMA accum; err ~2^-17 rel).
// A [NN][256] fp32 (cat or mid); W pre-split bf16 native [n][k] (so the
// B-fragment -- lane l = B[k][col=l&15] = W[l&15][k] -- reads k-contiguous).
// Block: 256 thr = 4 waves (2x2), out tile 128x128; per-wave 64x64 =
// 4x4 mfma_f32_16x16x32_bf16 tiles. BK=32, K=256. LDS 4x128x40 u16 = 40KB.
// A/B frag layout assumed: row/col = lane&15, k = (lane>>4)*8 + j.
// C/D layout (HW-verified m89): col = lane&15, row = (lane>>4)*4 + reg.
__global__ __launch_bounds__(256, 2) void k_mfma_mlp(const float* __restrict__ A,
                                                     const u16* __restrict__ Bhi,
                                                     const u16* __restrict__ Blo,
                                                     const float* __restrict__ bias,
                                                     float* __restrict__ C,
                                                     int ldC) {
    __shared__ u16 ahi[128 * 40], alo[128 * 40], bhi[128 * 40], blo[128 * 40];
    int t = threadIdx.x;
    int m0 = blockIdx.x * 128;
    int nbase = blockIdx.y * 128;
    int lane = t & 63, wid = t >> 6;
    int wm = wid >> 1, wn = wid & 1;
    int lr = lane & 15, lg = lane >> 4;

    f32x4 acc[4][4];
    #pragma unroll
    for (int i = 0; i < 4; ++i)
        #pragma unroll
        for (int j = 0; j < 4; ++j) acc[i][j] = (f32x4){0.f, 0.f, 0.f, 0.f};

    for (int k0 = 0; k0 < 256; k0 += 32) {
        __syncthreads();
        // stage A: 128 rows x 32 k, fp32 -> hi/lo u16. 4 f4 per thread.
        #pragma unroll
        for (int it = 0; it < 4; ++it) {
            int f = it * 256 + t;
            int m = f >> 3, q = f & 7;          // q: float4 index (4 k each)
            int node = m0 + m;
            float4 v = make_float4(0.f, 0.f, 0.f, 0.f);
            if (node < NN) v = ((const float4*)A)[(size_t)node * 64 + (k0 >> 2) + q];
            u16 h0, l0, h1_, l1_, h2_, l2_, h3, l3;
            bf16split(v.x, h0, l0);
            bf16split(v.y, h1_, l1_);
            bf16split(v.z, h2_, l2_);
            bf16split(v.w, h3, l3);
            uint* ph = (uint*)&ahi[m * 40 + q * 4];
            ph[0] = (uint)h0 | ((uint)h1_ << 16);
            ph[1] = (uint)h2_ | ((uint)h3 << 16);
            uint* pl = (uint*)&alo[m * 40 + q * 4];
            pl[0] = (uint)l0 | ((uint)l1_ << 16);
            pl[1] = (uint)l2_ | ((uint)l3 << 16);
        }
        // stage B: 128 n x 32 k from pre-split bf16 global ([n][256]).
        // 8 u16 (16B) per thread per half.
        #pragma unroll
        for (int it = 0; it < 2; ++it) {
            int f = it * 256 + t;
            int n = f >> 2, q = f & 3;          // q: 8-u16 chunk
            size_t gsrc = (size_t)(nbase + n) * 256 + k0 + q * 8;
            uint4 vh = *(const uint4*)&Bhi[gsrc];
            uint4 vl = *(const uint4*)&Blo[gsrc];
            *(uint4*)&bhi[n * 40 + q * 8] = vh;   // 16B-aligned: 80B row stride
            *(uint4*)&blo[n * 40 + q * 8] = vl;
        }
        __syncthreads();

        short8v afh[4], afl[4];
        #pragma unroll
        for (int mt = 0; mt < 4; ++mt) {
            int r = wm * 64 + mt * 16 + lr;
            afh[mt] = *(const short8v*)&ahi[r * 40 + lg * 8];
            afl[mt] = *(const short8v*)&alo[r * 40 + lg * 8];
        }
        #pragma unroll
        for (int nt = 0; nt < 4; ++nt) {
            int c = wn * 64 + nt * 16 + lr;
            short8v bfh = *(const short8v*)&bhi[c * 40 + lg * 8];
            short8v bfl = *(const short8v*)&blo[c * 40 + lg * 8];
            #pragma unroll
            for (int mt = 0; mt < 4; ++mt) {
                acc[mt][nt] = __builtin_amdgcn_mfma_f32_16x16x32_bf16(afh[mt], bfh, acc[mt][nt], 0, 0, 0);
                acc[mt][nt] = __builtin_amdgcn_mfma_f32_16x16x32_bf16(afh[mt], bfl, acc[mt][nt], 0, 0, 0);
                acc[mt][nt] = __builtin_amdgcn_mfma_f32_16x16x32_bf16(afl[mt], bfh, acc[mt][nt], 0, 0, 0);
            }
        }
    }

    // epilogue: relu(acc + bias) -> C
    #pragma unroll
    for (int nt = 0; nt < 4; ++nt) {
        int col = nbase + wn * 64 + nt * 16 + lr;
        float bv = bias[col];
        #pragma unroll
        for (int mt = 0; mt < 4; ++mt) {
            #pragma unroll
            for (int r = 0; r < 4; ++r) {
                int row = m0 + wm * 64 + mt * 16 + lg * 4 + r;
                if (row < NN) {
                    float v = fmaxf(acc[mt][nt][r] + bv, 0.f);
                    C[(size_t)row * ldC + col] = v;
                }
            }
        }
    }
}

// ---------------------------------------------------------------- launch
extern "C" void kernel_launch(void* const* d_in, const int* in_sizes, int n_in,
                              void* d_out, int out_size, void* d_ws, size_t ws_size,
                              hipStream_t stream) {
    const float* x   = (const float*)d_in[0];
    const int*   ei  = (const int*)d_in[1];
    const float* W1  = (const float*)d_in[2];
    const float* b1  = (const float*)d_in[3];
    const float* g1  = (const float*)d_in[4];
    const float* bt1 = (const float*)d_in[5];
    const float* W2  = (const float*)d_in[6];
    const float* b2  = (const float*)d_in[7];
    const float* g2  = (const float*)d_in[8];
    const float* bt2 = (const float*)d_in[9];
    const float* Wl1 = (const float*)d_in[10];
    const float* bl1 = (const float*)d_in[11];
    const float* Wl2 = (const float*)d_in[12];
    const float* bl2 = (const float*)d_in[13];
    float* out = (float*)d_out;

    float* ws    = (float*)d_ws;
    float* h1    = ws;
    float* h2    = ws + (size_t)NN * DD;
    float* mid   = ws;                          // reuse h region after branches
    float* cat   = ws + (size_t)2 * NN * DD;
    float* Wt1   = ws + (size_t)4 * NN * DD;
    float* Wt2   = Wt1 + 128 * 128;
    u16*   Wl1hi = (u16*)(Wt2 + 128 * 128);     // 16B-aligned (offset %16==0)
    u16*   Wl1lo = Wl1hi + 256 * 256;
    u16*   Wl2hi = Wl1lo + 256 * 256;
    u16*   Wl2lo = Wl2hi + 128 * 256;
    int*   off   = (int*)(Wl2lo + 128 * 256);
    int*   cur   = off + SCAN_N + 1;
    int*   idx   = cur + SCAN_N;
    int*   bsum  = idx + 2 * EE;

    k_prep<<<512, 256, 0, stream>>>(W1, W2, Wl1, Wl2, Wt1, Wt2,
                                    Wl1hi, Wl1lo, Wl2hi, Wl2lo);

    hipMemsetAsync(off, 0, (SCAN_N + 1) * sizeof(int), stream);
    k_count<<<EE / 256, 256, 0, stream>>>(ei, off);
    k_scan1<<<SCAN_BLOCKS, 256, 0, stream>>>(off, bsum);
    k_scan2<<<1, 256, 0, stream>>>(bsum);
    k_scan3<<<SCAN_BLOCKS, 256, 0, stream>>>(off, bsum, cur);
    k_fill<<<(EE / 256) * 8, 256, 0, stream>>>(ei, cur, idx);

    k_gather<<<SCAN_N / 8, 256, 0, stream>>>((const float4*)x, off, idx,
                                             (float4*)h1, (float4*)h2);

    int nb128 = (NN + 127) / 128;
    k_branch<<<dim3(nb128, 2), 256, 0, stream>>>(h1, h2, Wt1, Wt2,
                                                 b1, b2, g1, g2, bt1, bt2, cat);

    // merge MLP via bf16-split MFMA
    k_mfma_mlp<<<dim3(nb128, 2), 256, 0, stream>>>(cat, Wl1hi, Wl1lo, bl1, mid, 256);
    k_mfma_mlp<<<dim3(nb128, 1), 256, 0, stream>>>(mid, Wl2hi, Wl2lo, bl2, out, 128);
}

// Round 11
// 850.118 us; speedup vs baseline: 1.5719x; 1.0220x over previous
//
#include <hip/hip_runtime.h>
#include <hip/hip_bf16.h>

#define NN 100000
#define EE 1600000
#define DD 128
#define SCAN_N (2 * NN)
#define SCAN_BLOCKS ((SCAN_N + 1023) / 1024)   // 196
#define FILL_PASSES 4
#define FILL_RANGE (NN / FILL_PASSES)          // 25000

typedef unsigned short u16;
typedef __attribute__((ext_vector_type(8))) short short8v;
typedef __attribute__((ext_vector_type(4))) float f32x4;

__device__ inline void bf16split(float v, u16& hi, u16& lo) {
    __hip_bfloat16 h = __float2bfloat16(v);          // RNE
    hi = *reinterpret_cast<u16*>(&h);
    float r = v - __bfloat162float(h);
    __hip_bfloat16 l = __float2bfloat16(r);
    lo = *reinterpret_cast<u16*>(&l);
}

// ---------------------------------------------------------------- prep
// ALL weights bf16 hi/lo split in NATIVE [n][k] layout (MFMA B-frag wants
// W rows k-contiguous; no transposes anywhere anymore).
__global__ __launch_bounds__(256) void k_prep(const float* __restrict__ W1,
                                              const float* __restrict__ W2,
                                              const float* __restrict__ Wl1,
                                              const float* __restrict__ Wl2,
                                              u16* __restrict__ W1hi, u16* __restrict__ W1lo,
                                              u16* __restrict__ W2hi, u16* __restrict__ W2lo,
                                              u16* __restrict__ Wl1hi, u16* __restrict__ Wl1lo,
                                              u16* __restrict__ Wl2hi, u16* __restrict__ Wl2lo) {
    int tid = blockIdx.x * 256 + threadIdx.x;   // 131072 threads
    if (tid < 16384) {
        bf16split(W1[tid], W1hi[tid], W1lo[tid]);
    } else if (tid < 32768) {
        int i = tid - 16384;
        bf16split(W2[i], W2hi[i], W2lo[i]);
    } else if (tid < 98304) {
        int i = tid - 32768;                    // Wl1 [256][256]
        bf16split(Wl1[i], Wl1hi[i], Wl1lo[i]);
    } else {
        int i = tid - 98304;                    // Wl2 [128][256]
        bf16split(Wl2[i], Wl2hi[i], Wl2lo[i]);
    }
}

// ---------------------------------------------------------------- CSR build
__global__ __launch_bounds__(256) void k_count(const int* __restrict__ ei,
                                               int* __restrict__ off) {
    int e = blockIdx.x * 256 + threadIdx.x;
    int s = ei[e];
    int d = ei[EE + e];
    atomicAdd(&off[d], 1);
    atomicAdd(&off[NN + s], 1);
}

__global__ __launch_bounds__(256) void k_scan1(int* __restrict__ off,
                                               int* __restrict__ bsum) {
    __shared__ int s[256];
    int t = threadIdx.x;
    int base = blockIdx.x * 1024 + t * 4;
    int v[4];
    #pragma unroll
    for (int i = 0; i < 4; ++i) {
        int g = base + i;
        v[i] = (g < SCAN_N) ? off[g] : 0;
    }
    int local = v[0] + v[1] + v[2] + v[3];
    s[t] = local;
    __syncthreads();
    #pragma unroll
    for (int o = 1; o < 256; o <<= 1) {
        int add = (t >= o) ? s[t - o] : 0;
        __syncthreads();
        s[t] += add;
        __syncthreads();
    }
    int run = s[t] - local;
    #pragma unroll
    for (int i = 0; i < 4; ++i) {
        int g = base + i;
        if (g < SCAN_N) off[g] = run;
        run += v[i];
    }
    if (t == 0) bsum[blockIdx.x] = s[255];
}

__global__ __launch_bounds__(256) void k_scan2(int* __restrict__ bsum) {
    __shared__ int s[256];
    int t = threadIdx.x;
    int local = (t < SCAN_BLOCKS) ? bsum[t] : 0;
    s[t] = local;
    __syncthreads();
    #pragma unroll
    for (int o = 1; o < 256; o <<= 1) {
        int add = (t >= o) ? s[t - o] : 0;
        __syncthreads();
        s[t] += add;
        __syncthreads();
    }
    if (t < SCAN_BLOCKS) bsum[t] = s[t] - local;
}

__global__ __launch_bounds__(256) void k_scan3(int* __restrict__ off,
                                               const int* __restrict__ bsum,
                                               int* __restrict__ cur) {
    int t = threadIdx.x;
    int base = blockIdx.x * 1024 + t * 4;
    int add = bsum[blockIdx.x];
    #pragma unroll
    for (int i = 0; i < 4; ++i) {
        int g = base + i;
        if (g < SCAN_N) {
            int v = off[g] + add;
            off[g] = v;
            cur[g] = v;
        }
    }
    if (blockIdx.x == 0 && t == 0) off[SCAN_N] = 2 * EE;
}

__global__ __launch_bounds__(256) void k_fill(const int* __restrict__ ei,
                                              int* __restrict__ cur,
                                              int* __restrict__ idx) {
    int b = blockIdx.x;
    int w = b >> 3, myk = b & 7;
    int e = w * 256 + threadIdx.x;
    int s = ei[e];
    int d = ei[EE + e];
    bool ownD = (((d >> 3) & 7) == myk);
    bool ownS = (((s >> 3) & 7) == myk);
    #pragma unroll
    for (int p = 0; p < FILL_PASSES; ++p) {
        if (ownD && d >= p * FILL_RANGE && d < (p + 1) * FILL_RANGE) {
            int p1 = atomicAdd(&cur[d], 1);
            idx[p1] = s;
        }
        if (ownS && s >= p * FILL_RANGE && s < (p + 1) * FILL_RANGE) {
            int p2 = atomicAdd(&cur[NN + s], 1);
            idx[p2] = d;
        }
        __syncthreads();
    }
}

// ---------------------------------------------------------------- gather
// Unroll 8: 8 independent row-loads in flight (was 4).
__global__ __launch_bounds__(256) void k_gather(const float4* __restrict__ x4,
                                                const int* __restrict__ off,
                                                const int* __restrict__ idx,
                                                float4* __restrict__ h1,
                                                float4* __restrict__ h2) {
    int t = threadIdx.x;
    int g = blockIdx.x * 8 + (t >> 5);
    int c = t & 31;
    int n = (g < NN) ? g : g - NN;
    int o0 = off[g], o1 = off[g + 1];
    float4 acc = x4[n * 32 + c];
    int j = o0;
    for (; j + 8 <= o1; j += 8) {
        float4 v0 = x4[idx[j + 0] * 32 + c];
        float4 v1 = x4[idx[j + 1] * 32 + c];
        float4 v2 = x4[idx[j + 2] * 32 + c];
        float4 v3 = x4[idx[j + 3] * 32 + c];
        float4 v4 = x4[idx[j + 4] * 32 + c];
        float4 v5 = x4[idx[j + 5] * 32 + c];
        float4 v6 = x4[idx[j + 6] * 32 + c];
        float4 v7 = x4[idx[j + 7] * 32 + c];
        acc.x += v0.x + v1.x + v2.x + v3.x + v4.x + v5.x + v6.x + v7.x;
        acc.y += v0.y + v1.y + v2.y + v3.y + v4.y + v5.y + v6.y + v7.y;
        acc.z += v0.z + v1.z + v2.z + v3.z + v4.z + v5.z + v6.z + v7.z;
        acc.w += v0.w + v1.w + v2.w + v3.w + v4.w + v5.w + v6.w + v7.w;
    }
    for (; j + 4 <= o1; j += 4) {
        float4 v0 = x4[idx[j + 0] * 32 + c];
        float4 v1 = x4[idx[j + 1] * 32 + c];
        float4 v2 = x4[idx[j + 2] * 32 + c];
        float4 v3 = x4[idx[j + 3] * 32 + c];
        acc.x += v0.x + v1.x + v2.x + v3.x;
        acc.y += v0.y + v1.y + v2.y + v3.y;
        acc.z += v0.z + v1.z + v2.z + v3.z;
        acc.w += v0.w + v1.w + v2.w + v3.w;
    }
    for (; j < o1; ++j) {
        float4 v = x4[idx[j] * 32 + c];
        acc.x += v.x; acc.y += v.y; acc.z += v.z; acc.w += v.w;
    }
    float4* hout = (g < NN) ? h1 : h2;
    hout[n * 32 + c] = acc;
}

// ---------------------------------------------------------------- branch (MFMA)
// cat[:,colOff..] = h + relu(LN(h @ W^T + bias)) via bf16 hi/lo split MFMA.
// Tile 128x128, 4 waves (2x2), per-wave 64x64 = 4x4 mfma_f32_16x16x32_bf16.
// K=128 in 4 steps of 32. LN: in-thread sum over nt + shfl_xor over the 16
// lr lanes + LDS cross-wave (wn) combine -> full 128-col row stats.
// C/D layout (HW-verified): col=lane&15, row=(lane>>4)*4+reg.
__global__ __launch_bounds__(256, 2) void k_branch_mfma(const float* __restrict__ h1,
                                                        const float* __restrict__ h2,
                                                        const u16* __restrict__ W1hi,
                                                        const u16* __restrict__ W1lo,
                                                        const u16* __restrict__ W2hi,
                                                        const u16* __restrict__ W2lo,
                                                        const float* __restrict__ bias1,
                                                        const float* __restrict__ bias2,
                                                        const float* __restrict__ gam1,
                                                        const float* __restrict__ gam2,
                                                        const float* __restrict__ beta1,
                                                        const float* __restrict__ beta2,
                                                        float* __restrict__ cat) {
    const int br = blockIdx.y;
    const float* h    = br ? h2    : h1;
    const u16*  Whi   = br ? W2hi  : W1hi;
    const u16*  Wlo   = br ? W2lo  : W1lo;
    const float* bias = br ? bias2 : bias1;
    const float* gam  = br ? gam2  : gam1;
    const float* beta = br ? beta2 : beta1;
    const int colOff  = br ? 128 : 0;

    __shared__ u16 ahi[128 * 40], alo[128 * 40], bhi[128 * 40], blo[128 * 40];
    __shared__ float red[2][128][2];            // [wn][row][s,q]
    int t = threadIdx.x;
    int m0 = blockIdx.x * 128;
    int lane = t & 63, wid = t >> 6;
    int wm = wid >> 1, wn = wid & 1;
    int lr = lane & 15, lg = lane >> 4;

    f32x4 acc[4][4];
    #pragma unroll
    for (int i = 0; i < 4; ++i)
        #pragma unroll
        for (int j = 0; j < 4; ++j) acc[i][j] = (f32x4){0.f, 0.f, 0.f, 0.f};

    for (int k0 = 0; k0 < 128; k0 += 32) {
        __syncthreads();
        // stage A (h): 128 rows x 32 k, fp32 -> hi/lo split
        #pragma unroll
        for (int it = 0; it < 4; ++it) {
            int f = it * 256 + t;
            int m = f >> 3, q = f & 7;
            int node = m0 + m;
            float4 v = make_float4(0.f, 0.f, 0.f, 0.f);
            if (node < NN) v = ((const float4*)h)[(size_t)node * 32 + (k0 >> 2) + q];
            u16 h0, l0, h1_, l1_, h2_, l2_, h3, l3;
            bf16split(v.x, h0, l0);
            bf16split(v.y, h1_, l1_);
            bf16split(v.z, h2_, l2_);
            bf16split(v.w, h3, l3);
            uint* ph = (uint*)&ahi[m * 40 + q * 4];
            ph[0] = (uint)h0 | ((uint)h1_ << 16);
            ph[1] = (uint)h2_ | ((uint)h3 << 16);
            uint* pl = (uint*)&alo[m * 40 + q * 4];
            pl[0] = (uint)l0 | ((uint)l1_ << 16);
            pl[1] = (uint)l2_ | ((uint)l3 << 16);
        }
        // stage B (W pre-split, [128][128]): 128 n x 32 k
        #pragma unroll
        for (int it = 0; it < 2; ++it) {
            int f = it * 256 + t;
            int n = f >> 2, q = f & 3;
            int gsrc = n * 128 + k0 + q * 8;
            *(uint4*)&bhi[n * 40 + q * 8] = *(const uint4*)&Whi[gsrc];
            *(uint4*)&blo[n * 40 + q * 8] = *(const uint4*)&Wlo[gsrc];
        }
        __syncthreads();

        short8v afh[4], afl[4];
        #pragma unroll
        for (int mt = 0; mt < 4; ++mt) {
            int r = wm * 64 + mt * 16 + lr;
            afh[mt] = *(const short8v*)&ahi[r * 40 + lg * 8];
            afl[mt] = *(const short8v*)&alo[r * 40 + lg * 8];
        }
        #pragma unroll
        for (int nt = 0; nt < 4; ++nt) {
            int c = wn * 64 + nt * 16 + lr;
            short8v bfh = *(const short8v*)&bhi[c * 40 + lg * 8];
            short8v bfl = *(const short8v*)&blo[c * 40 + lg * 8];
            #pragma unroll
            for (int mt = 0; mt < 4; ++mt) {
                acc[mt][nt] = __builtin_amdgcn_mfma_f32_16x16x32_bf16(afh[mt], bfh, acc[mt][nt], 0, 0, 0);
                acc[mt][nt] = __builtin_amdgcn_mfma_f32_16x16x32_bf16(afh[mt], bfl, acc[mt][nt], 0, 0, 0);
                acc[mt][nt] = __builtin_amdgcn_mfma_f32_16x16x32_bf16(afl[mt], bfh, acc[mt][nt], 0, 0, 0);
            }
        }
    }

    // ---- epilogue: +bias, LN row-stats, relu, residual, write cat ----
    float breg[4], greg[4], btreg[4];
    #pragma unroll
    for (int nt = 0; nt < 4; ++nt) {
        int col = wn * 64 + nt * 16 + lr;
        breg[nt]  = bias[col];
        greg[nt]  = gam[col];
        btreg[nt] = beta[col];
    }
    #pragma unroll
    for (int mt = 0; mt < 4; ++mt)
        #pragma unroll
        for (int nt = 0; nt < 4; ++nt)
            #pragma unroll
            for (int r = 0; r < 4; ++r) acc[mt][nt][r] += breg[nt];

    // partial row sums over this wave's 64 cols
    #pragma unroll
    for (int mt = 0; mt < 4; ++mt) {
        #pragma unroll
        for (int r = 0; r < 4; ++r) {
            float s = 0.f, q = 0.f;
            #pragma unroll
            for (int nt = 0; nt < 4; ++nt) {
                float v = acc[mt][nt][r];
                s += v;
                q += v * v;
            }
            #pragma unroll
            for (int o = 1; o < 16; o <<= 1) {
                s += __shfl_xor(s, o);
                q += __shfl_xor(q, o);
            }
            if (lr == 0) {
                int row = wm * 64 + mt * 16 + lg * 4 + r;
                red[wn][row][0] = s;
                red[wn][row][1] = q;
            }
        }
    }
    __syncthreads();

    #pragma unroll
    for (int mt = 0; mt < 4; ++mt) {
        #pragma unroll
        for (int r = 0; r < 4; ++r) {
            int row = wm * 64 + mt * 16 + lg * 4 + r;
            int node = m0 + row;
            float s = red[0][row][0] + red[1][row][0];
            float q = red[0][row][1] + red[1][row][1];
            float mu  = s * (1.f / 128.f);
            float var = q * (1.f / 128.f) - mu * mu;
            float rs  = rsqrtf(var + 1e-5f);
            if (node < NN) {
                const float* hrow = &h[(size_t)node * 128];
                #pragma unroll
                for (int nt = 0; nt < 4; ++nt) {
                    int col = wn * 64 + nt * 16 + lr;
                    float y = (acc[mt][nt][r] - mu) * rs * greg[nt] + btreg[nt];
                    float o_ = hrow[col] + fmaxf(y, 0.f);
                    cat[(size_t)node * 256 + colOff + col] = o_;
                }
            }
        }
    }
}

// ---------------------------------------------------------------- MFMA MLP (unchanged)
__global__ __launch_bounds__(256, 2) void k_mfma_mlp(const float* __restrict__ A,
                                                     const u16* __restrict__ Bhi,
                                                     const u16* __restrict__ Blo,
                                                     const float* __restrict__ bias,
                                                     float* __restrict__ C,
                                                     int ldC) {
    __shared__ u16 ahi[128 * 40], alo[128 * 40], bhi[128 * 40], blo[128 * 40];
    int t = threadIdx.x;
    int m0 = blockIdx.x * 128;
    int nbase = blockIdx.y * 128;
    int lane = t & 63, wid = t >> 6;
    int wm = wid >> 1, wn = wid & 1;
    int lr = lane & 15, lg = lane >> 4;

    f32x4 acc[4][4];
    #pragma unroll
    for (int i = 0; i < 4; ++i)
        #pragma unroll
        for (int j = 0; j < 4; ++j) acc[i][j] = (f32x4){0.f, 0.f, 0.f, 0.f};

    for (int k0 = 0; k0 < 256; k0 += 32) {
        __syncthreads();
        #pragma unroll
        for (int it = 0; it < 4; ++it) {
            int f = it * 256 + t;
            int m = f >> 3, q = f & 7;
            int node = m0 + m;
            float4 v = make_float4(0.f, 0.f, 0.f, 0.f);
            if (node < NN) v = ((const float4*)A)[(size_t)node * 64 + (k0 >> 2) + q];
            u16 h0, l0, h1_, l1_, h2_, l2_, h3, l3;
            bf16split(v.x, h0, l0);
            bf16split(v.y, h1_, l1_);
            bf16split(v.z, h2_, l2_);
            bf16split(v.w, h3, l3);
            uint* ph = (uint*)&ahi[m * 40 + q * 4];
            ph[0] = (uint)h0 | ((uint)h1_ << 16);
            ph[1] = (uint)h2_ | ((uint)h3 << 16);
            uint* pl = (uint*)&alo[m * 40 + q * 4];
            pl[0] = (uint)l0 | ((uint)l1_ << 16);
            pl[1] = (uint)l2_ | ((uint)l3 << 16);
        }
        #pragma unroll
        for (int it = 0; it < 2; ++it) {
            int f = it * 256 + t;
            int n = f >> 2, q = f & 3;
            size_t gsrc = (size_t)(nbase + n) * 256 + k0 + q * 8;
            *(uint4*)&bhi[n * 40 + q * 8] = *(const uint4*)&Bhi[gsrc];
            *(uint4*)&blo[n * 40 + q * 8] = *(const uint4*)&Blo[gsrc];
        }
        __syncthreads();

        short8v afh[4], afl[4];
        #pragma unroll
        for (int mt = 0; mt < 4; ++mt) {
            int r = wm * 64 + mt * 16 + lr;
            afh[mt] = *(const short8v*)&ahi[r * 40 + lg * 8];
            afl[mt] = *(const short8v*)&alo[r * 40 + lg * 8];
        }
        #pragma unroll
        for (int nt = 0; nt < 4; ++nt) {
            int c = wn * 64 + nt * 16 + lr;
            short8v bfh = *(const short8v*)&bhi[c * 40 + lg * 8];
            short8v bfl = *(const short8v*)&blo[c * 40 + lg * 8];
            #pragma unroll
            for (int mt = 0; mt < 4; ++mt) {
                acc[mt][nt] = __builtin_amdgcn_mfma_f32_16x16x32_bf16(afh[mt], bfh, acc[mt][nt], 0, 0, 0);
                acc[mt][nt] = __builtin_amdgcn_mfma_f32_16x16x32_bf16(afh[mt], bfl, acc[mt][nt], 0, 0, 0);
                acc[mt][nt] = __builtin_amdgcn_mfma_f32_16x16x32_bf16(afl[mt], bfh, acc[mt][nt], 0, 0, 0);
            }
        }
    }

    #pragma unroll
    for (int nt = 0; nt < 4; ++nt) {
        int col = nbase + wn * 64 + nt * 16 + lr;
        float bv = bias[col];
        #pragma unroll
        for (int mt = 0; mt < 4; ++mt) {
            #pragma unroll
            for (int r = 0; r < 4; ++r) {
                int row = m0 + wm * 64 + mt * 16 + lg * 4 + r;
                if (row < NN) {
                    float v = fmaxf(acc[mt][nt][r] + bv, 0.f);
                    C[(size_t)row * ldC + col] = v;
                }
            }
        }
    }
}

// ---------------------------------------------------------------- launch
extern "C" void kernel_launch(void* const* d_in, const int* in_sizes, int n_in,
                              void* d_out, int out_size, void* d_ws, size_t ws_size,
                              hipStream_t stream) {
    const float* x   = (const float*)d_in[0];
    const int*   ei  = (const int*)d_in[1];
    const float* W1  = (const float*)d_in[2];
    const float* b1  = (const float*)d_in[3];
    const float* g1  = (const float*)d_in[4];
    const float* bt1 = (const float*)d_in[5];
    const float* W2  = (const float*)d_in[6];
    const float* b2  = (const float*)d_in[7];
    const float* g2  = (const float*)d_in[8];
    const float* bt2 = (const float*)d_in[9];
    const float* Wl1 = (const float*)d_in[10];
    const float* bl1 = (const float*)d_in[11];
    const float* Wl2 = (const float*)d_in[12];
    const float* bl2 = (const float*)d_in[13];
    float* out = (float*)d_out;

    float* ws    = (float*)d_ws;
    float* h1    = ws;
    float* h2    = ws + (size_t)NN * DD;
    float* mid   = ws;                          // reuse h region after branches
    float* cat   = ws + (size_t)2 * NN * DD;
    u16*   W1hi  = (u16*)(ws + (size_t)4 * NN * DD);
    u16*   W1lo  = W1hi + 16384;
    u16*   W2hi  = W1lo + 16384;
    u16*   W2lo  = W2hi + 16384;
    u16*   Wl1hi = W2lo + 16384;
    u16*   Wl1lo = Wl1hi + 65536;
    u16*   Wl2hi = Wl1lo + 65536;
    u16*   Wl2lo = Wl2hi + 32768;
    int*   off   = (int*)(Wl2lo + 32768);
    int*   cur   = off + SCAN_N + 1;
    int*   idx   = cur + SCAN_N;
    int*   bsum  = idx + 2 * EE;

    k_prep<<<512, 256, 0, stream>>>(W1, W2, Wl1, Wl2,
                                    W1hi, W1lo, W2hi, W2lo,
                                    Wl1hi, Wl1lo, Wl2hi, Wl2lo);

    hipMemsetAsync(off, 0, (SCAN_N + 1) * sizeof(int), stream);
    k_count<<<EE / 256, 256, 0, stream>>>(ei, off);
    k_scan1<<<SCAN_BLOCKS, 256, 0, stream>>>(off, bsum);
    k_scan2<<<1, 256, 0, stream>>>(bsum);
    k_scan3<<<SCAN_BLOCKS, 256, 0, stream>>>(off, bsum, cur);
    k_fill<<<(EE / 256) * 8, 256, 0, stream>>>(ei, cur, idx);

    k_gather<<<SCAN_N / 8, 256, 0, stream>>>((const float4*)x, off, idx,
                                             (float4*)h1, (float4*)h2);

    int nb128 = (NN + 127) / 128;
    k_branch_mfma<<<dim3(nb128, 2), 256, 0, stream>>>(h1, h2,
                                                      W1hi, W1lo, W2hi, W2lo,
                                                      b1, b2, g1, g2, bt1, bt2, cat);

    k_mfma_mlp<<<dim3(nb128, 2), 256, 0, stream>>>(cat, Wl1hi, Wl1lo, bl1, mid, 256);
    k_mfma_mlp<<<dim3(nb128, 1), 256, 0, stream>>>(mid, Wl2hi, Wl2lo, bl2, out, 128);
}